// Round 11
// baseline (228.140 us; speedup 1.0000x reference)
//
#include <hip/hip_runtime.h>
#include <cmath>

#define Bb 8192
#define Dd 2048
#define Rr 64
#define Ee 4
#define Ll 3

typedef __bf16 bf16x8 __attribute__((ext_vector_type(8)));
typedef float f32x4 __attribute__((ext_vector_type(4)));
typedef unsigned short u16x8 __attribute__((ext_vector_type(8)));
typedef unsigned short u16x4 __attribute__((ext_vector_type(4)));

__device__ __forceinline__ unsigned short f2bf(float f){
  unsigned u = __builtin_bit_cast(unsigned, f);
  u += 0x7fffu + ((u >> 16) & 1u);
  return (unsigned short)(u >> 16);
}
__device__ __forceinline__ float bf2f(unsigned short h){
  return __builtin_bit_cast(float, ((unsigned)h) << 16);
}

// ---------------- prep: transpose/cast weights ----------------
__global__ __launch_bounds__(256) void prep_w_k(const float* __restrict__ U,
                                                const float* __restrict__ V,
                                                const float* __restrict__ C,
                                                const float* __restrict__ gw,
                                                unsigned short* __restrict__ VfT,
                                                unsigned short* __restrict__ UfT,
                                                unsigned short* __restrict__ cb16,
                                                unsigned short* __restrict__ gw16){
  const int NV = Ll * 256 * Dd;
  const int NU = Ll * Dd * 256;
  const int NC = Ll * Ee * Rr * Rr;
  const int NG = Ee * Dd;
  const int total = NV + NU + NC + NG;
  for (int idx = blockIdx.x * blockDim.x + threadIdx.x; idx < total; idx += gridDim.x * blockDim.x){
    if (idx < NV){
      int l = idx / (256 * Dd); int rem = idx - l * 256 * Dd;
      int n = rem / Dd, d = rem - n * Dd;
      int e = n >> 6, r = n & 63;
      VfT[idx] = f2bf(V[(((size_t)l * Ee + e) * Dd + d) * Rr + r]);
    } else if (idx < NV + NU){
      int j = idx - NV;
      int l = j / (Dd * 256); int rem = j - l * Dd * 256;
      int d = rem / 256, k = rem - d * 256;
      int e = k >> 6, s = k & 63;
      UfT[j] = f2bf(U[(((size_t)l * Ee + e) * Dd + d) * Rr + s]);
    } else if (idx < NV + NU + NC){
      int j = idx - NV - NU;
      cb16[j] = f2bf(C[j]);
    } else {
      int j = idx - NV - NU - NC;
      gw16[j] = f2bf(gw[j]);
    }
  }
}

// ---------------- fused cast + layer-0 gate: one wave per row ----------------
__global__ __launch_bounds__(256) void cast_gate_k(const float* __restrict__ x,
                                                   unsigned short* __restrict__ xb0,
                                                   const unsigned short* __restrict__ gw16,
                                                   float* __restrict__ gs){
  const int lane = threadIdx.x & 63;
  const int w = threadIdx.x >> 6;
  const int row = blockIdx.x * 4 + w;
  float s0 = 0.f, s1 = 0.f, s2 = 0.f, s3 = 0.f;
  #pragma unroll
  for (int c = 0; c < 4; c++){
    const int k = c * 512 + lane * 8;
    const float* xr = x + (size_t)row * Dd + k;
    f32x4 v0 = *(const f32x4*)xr;
    f32x4 v1 = *(const f32x4*)(xr + 4);
    float xf[8];
    u16x8 ob;
    #pragma unroll
    for (int u = 0; u < 4; u++){
      xf[u] = v0[u]; xf[4 + u] = v1[u];
      ob[u] = f2bf(v0[u]); ob[4 + u] = f2bf(v1[u]);
    }
    *(u16x8*)(xb0 + (size_t)row * Dd + k) = ob;
    u16x8 g0v = *(const u16x8*)(gw16 + 0 * Dd + k);
    u16x8 g1v = *(const u16x8*)(gw16 + 1 * Dd + k);
    u16x8 g2v = *(const u16x8*)(gw16 + 2 * Dd + k);
    u16x8 g3v = *(const u16x8*)(gw16 + 3 * Dd + k);
    #pragma unroll
    for (int u = 0; u < 8; u++){
      s0 += xf[u] * bf2f(g0v[u]);
      s1 += xf[u] * bf2f(g1v[u]);
      s2 += xf[u] * bf2f(g2v[u]);
      s3 += xf[u] * bf2f(g3v[u]);
    }
  }
  #pragma unroll
  for (int m = 1; m < 64; m <<= 1){
    s0 += __shfl_xor(s0, m, 64);
    s1 += __shfl_xor(s1, m, 64);
    s2 += __shfl_xor(s2, m, 64);
    s3 += __shfl_xor(s3, m, 64);
  }
  if (lane == 0){
    float mx = fmaxf(fmaxf(s0, s1), fmaxf(s2, s3));
    float e0 = __expf(s0 - mx), e1 = __expf(s1 - mx), e2 = __expf(s2 - mx), e3 = __expf(s3 - mx);
    float inv = 1.f / (e0 + e1 + e2 + e3);
    f32x4 g; g[0] = e0 * inv; g[1] = e1 * inv; g[2] = e2 * inv; g[3] = e3 * inv;
    *(f32x4*)(gs + (size_t)row * 4) = g;
  }
}

// ---------------- gate (fallback, fp32 input) ----------------
__global__ __launch_bounds__(256) void gate_k(const float* __restrict__ xv,
                                              const unsigned short* __restrict__ gw16,
                                              float* __restrict__ gs){
  const int lane = threadIdx.x & 63;
  const int w = threadIdx.x >> 6;
  const int row = blockIdx.x * 4 + w;
  float s0 = 0.f, s1 = 0.f, s2 = 0.f, s3 = 0.f;
  #pragma unroll
  for (int c = 0; c < 4; c++){
    const int k = c * 512 + lane * 8;
    const float* xr = xv + (size_t)row * Dd + k;
    f32x4 v0 = *(const f32x4*)xr;
    f32x4 v1 = *(const f32x4*)(xr + 4);
    float xf[8];
    #pragma unroll
    for (int u = 0; u < 4; u++){ xf[u] = v0[u]; xf[4 + u] = v1[u]; }
    u16x8 g0v = *(const u16x8*)(gw16 + 0 * Dd + k);
    u16x8 g1v = *(const u16x8*)(gw16 + 1 * Dd + k);
    u16x8 g2v = *(const u16x8*)(gw16 + 2 * Dd + k);
    u16x8 g3v = *(const u16x8*)(gw16 + 3 * Dd + k);
    #pragma unroll
    for (int u = 0; u < 8; u++){
      s0 += xf[u] * bf2f(g0v[u]);
      s1 += xf[u] * bf2f(g1v[u]);
      s2 += xf[u] * bf2f(g2v[u]);
      s3 += xf[u] * bf2f(g3v[u]);
    }
  }
  #pragma unroll
  for (int m = 1; m < 64; m <<= 1){
    s0 += __shfl_xor(s0, m, 64);
    s1 += __shfl_xor(s1, m, 64);
    s2 += __shfl_xor(s2, m, 64);
    s3 += __shfl_xor(s3, m, 64);
  }
  if (lane == 0){
    float mx = fmaxf(fmaxf(s0, s1), fmaxf(s2, s3));
    float e0 = __expf(s0 - mx), e1 = __expf(s1 - mx), e2 = __expf(s2 - mx), e3 = __expf(s3 - mx);
    float inv = 1.f / (e0 + e1 + e2 + e3);
    f32x4 g; g[0] = e0 * inv; g[1] = e1 * inv; g[2] = e2 * inv; g[3] = e3 * inv;
    *(f32x4*)(gs + (size_t)row * 4) = g;
  }
}

// ============ G1: T = X @ VfT, split-K=4, bf16 partials, BK=64 ============
template<bool AF32>
__global__ __launch_bounds__(256) void gemm1_k(const void* __restrict__ Av,
                                               const unsigned short* __restrict__ BT,
                                               unsigned short* __restrict__ vxp){
  const int bm0 = blockIdx.x * 64;
  const int bn0 = blockIdx.y * 128;
  const int z   = blockIdx.z;
  const int kc0 = z * 512;
  const int tid = threadIdx.x;
  const int lane = tid & 63;
  const int wv = tid >> 6;
  const int wm = wv >> 1, wn = wv & 1;

  __shared__ __align__(16) char smraw[27648];
  unsigned short (*As)[72] = (unsigned short (*)[72])smraw;            // 9216 B
  unsigned short (*Bs)[72] = (unsigned short (*)[72])(smraw + 9216);   // 18432 B
  float (*epi)[132] = (float (*)[132])smraw;                           // 16896 B (half-tile)

  f32x4 acc[2][4] = {};
  const int arow = tid >> 2;
  const int aseg = tid & 3;

  const float* Af = (const float*)Av;
  const unsigned short* Ab = (const unsigned short*)Av;

  f32x4 a4[4]; u16x8 ar[2]; u16x8 br[4];
  if constexpr (AF32){
    #pragma unroll
    for (int j = 0; j < 4; j++)
      a4[j] = *(const f32x4*)(Af + (size_t)(bm0 + arow) * Dd + kc0 + aseg * 16 + j * 4);
  } else {
    ar[0] = *(const u16x8*)(Ab + (size_t)(bm0 + arow) * Dd + kc0 + aseg * 16);
    ar[1] = *(const u16x8*)(Ab + (size_t)(bm0 + arow) * Dd + kc0 + aseg * 16 + 8);
  }
  br[0] = *(const u16x8*)(BT + (size_t)(bn0 + arow) * Dd + kc0 + aseg * 16);
  br[1] = *(const u16x8*)(BT + (size_t)(bn0 + arow) * Dd + kc0 + aseg * 16 + 8);
  br[2] = *(const u16x8*)(BT + (size_t)(bn0 + arow + 64) * Dd + kc0 + aseg * 16);
  br[3] = *(const u16x8*)(BT + (size_t)(bn0 + arow + 64) * Dd + kc0 + aseg * 16 + 8);

  for (int k0 = kc0; k0 < kc0 + 512; k0 += 64){
    __syncthreads();
    if constexpr (AF32){
      u16x8 av0, av1;
      #pragma unroll
      for (int j = 0; j < 4; j++){
        av0[j] = f2bf(a4[0][j]); av0[4 + j] = f2bf(a4[1][j]);
        av1[j] = f2bf(a4[2][j]); av1[4 + j] = f2bf(a4[3][j]);
      }
      *(u16x8*)(&As[arow][aseg * 16])     = av0;
      *(u16x8*)(&As[arow][aseg * 16 + 8]) = av1;
    } else {
      *(u16x8*)(&As[arow][aseg * 16])     = ar[0];
      *(u16x8*)(&As[arow][aseg * 16 + 8]) = ar[1];
    }
    *(u16x8*)(&Bs[arow][aseg * 16])          = br[0];
    *(u16x8*)(&Bs[arow][aseg * 16 + 8])      = br[1];
    *(u16x8*)(&Bs[arow + 64][aseg * 16])     = br[2];
    *(u16x8*)(&Bs[arow + 64][aseg * 16 + 8]) = br[3];
    __syncthreads();

    int kn = k0 + 64;
    if (kn < kc0 + 512){
      if constexpr (AF32){
        #pragma unroll
        for (int j = 0; j < 4; j++)
          a4[j] = *(const f32x4*)(Af + (size_t)(bm0 + arow) * Dd + kn + aseg * 16 + j * 4);
      } else {
        ar[0] = *(const u16x8*)(Ab + (size_t)(bm0 + arow) * Dd + kn + aseg * 16);
        ar[1] = *(const u16x8*)(Ab + (size_t)(bm0 + arow) * Dd + kn + aseg * 16 + 8);
      }
      br[0] = *(const u16x8*)(BT + (size_t)(bn0 + arow) * Dd + kn + aseg * 16);
      br[1] = *(const u16x8*)(BT + (size_t)(bn0 + arow) * Dd + kn + aseg * 16 + 8);
      br[2] = *(const u16x8*)(BT + (size_t)(bn0 + arow + 64) * Dd + kn + aseg * 16);
      br[3] = *(const u16x8*)(BT + (size_t)(bn0 + arow + 64) * Dd + kn + aseg * 16 + 8);
    }

    #pragma unroll
    for (int ks = 0; ks < 2; ks++){
      bf16x8 af[2];
      #pragma unroll
      for (int mi = 0; mi < 2; mi++)
        af[mi] = *reinterpret_cast<const bf16x8*>(&As[wm * 32 + mi * 16 + (lane & 15)][ks * 32 + (lane >> 4) * 8]);
      #pragma unroll
      for (int nj = 0; nj < 4; nj++){
        bf16x8 bfr = *reinterpret_cast<const bf16x8*>(&Bs[wn * 64 + nj * 16 + (lane & 15)][ks * 32 + (lane >> 4) * 8]);
        #pragma unroll
        for (int mi = 0; mi < 2; mi++)
          acc[mi][nj] = __builtin_amdgcn_mfma_f32_16x16x32_bf16(af[mi], bfr, acc[mi][nj], 0, 0, 0);
      }
    }
  }

  unsigned short* outz = vxp + (size_t)z * Bb * 256;
  #pragma unroll
  for (int h = 0; h < 2; h++){
    __syncthreads();
    if (wm == h){
      #pragma unroll
      for (int mi = 0; mi < 2; mi++)
        #pragma unroll
        for (int nj = 0; nj < 4; nj++)
          #pragma unroll
          for (int q = 0; q < 4; q++)
            epi[mi * 16 + (lane >> 4) * 4 + q][wn * 64 + nj * 16 + (lane & 15)] = acc[mi][nj][q];
    }
    __syncthreads();
    #pragma unroll
    for (int c = 0; c < 4; c++){
      int idx = c * 256 + tid;
      int r = idx >> 5;
      int col = (idx & 31) * 4;
      f32x4 v = *(const f32x4*)&epi[r][col];
      u16x4 ov;
      #pragma unroll
      for (int j = 0; j < 4; j++) ov[j] = f2bf(v[j]);
      *(u16x4*)(outz + (size_t)(bm0 + h * 32 + r) * 256 + bn0 + col) = ov;
    }
  }
}

// ============ G2: block-diag C; sums bf16 partials; reads gsb ============
__global__ __launch_bounds__(256) void gemm2_k(const unsigned short* __restrict__ vxp,
                                               const unsigned short* __restrict__ cb,
                                               const float* __restrict__ gsb,
                                               unsigned short* __restrict__ wb){
  const int bm0 = blockIdx.x * 64;
  const int e   = blockIdx.y;
  const int tid = threadIdx.x;
  const int lane = tid & 63;
  const int wv = tid >> 6;
  const int wm = wv >> 1, wn = wv & 1;

  __shared__ __align__(16) char smraw[19456];
  unsigned short (*As)[72] = (unsigned short (*)[72])smraw;            // 9216
  unsigned short (*Bs)[72] = (unsigned short (*)[72])(smraw + 9216);   // 9216
  float (*gs_l)[4] = (float (*)[4])(smraw + 18432);                    // 1024
  unsigned short (*epi)[72] = (unsigned short (*)[72])smraw;           // union As

  if (tid < 64) *(f32x4*)&gs_l[tid][0] = *(const f32x4*)(gsb + (size_t)(bm0 + tid) * 4);

  const int arow = tid >> 2;
  const int aseg = tid & 3;

  float tv[16];
  #pragma unroll
  for (int j = 0; j < 16; j++) tv[j] = 0.f;
  #pragma unroll
  for (int z = 0; z < 4; z++){
    const unsigned short* vz = vxp + ((size_t)z * Bb + bm0 + arow) * 256 + e * 64 + aseg * 16;
    u16x8 p0 = *(const u16x8*)vz;
    u16x8 p1 = *(const u16x8*)(vz + 8);
    #pragma unroll
    for (int j = 0; j < 8; j++){ tv[j] += bf2f(p0[j]); tv[8 + j] += bf2f(p1[j]); }
  }
  u16x8 av0, av1;
  #pragma unroll
  for (int j = 0; j < 4; j++){
    av0[j] = f2bf(tanhf(tv[j]));     av0[4 + j] = f2bf(tanhf(tv[4 + j]));
    av1[j] = f2bf(tanhf(tv[8 + j])); av1[4 + j] = f2bf(tanhf(tv[12 + j]));
  }
  *(u16x8*)(&As[arow][aseg * 16]) = av0;
  *(u16x8*)(&As[arow][aseg * 16 + 8]) = av1;
  *(u16x8*)(&Bs[arow][aseg * 16])     = *(const u16x8*)(cb + e * 4096 + arow * 64 + aseg * 16);
  *(u16x8*)(&Bs[arow][aseg * 16 + 8]) = *(const u16x8*)(cb + e * 4096 + arow * 64 + aseg * 16 + 8);
  __syncthreads();

  f32x4 acc[2][2] = {};
  #pragma unroll
  for (int kk = 0; kk < 2; kk++){
    bf16x8 af[2];
    #pragma unroll
    for (int mi = 0; mi < 2; mi++)
      af[mi] = *reinterpret_cast<const bf16x8*>(&As[wm * 32 + mi * 16 + (lane & 15)][kk * 32 + (lane >> 4) * 8]);
    #pragma unroll
    for (int nj = 0; nj < 2; nj++){
      bf16x8 bfr = *reinterpret_cast<const bf16x8*>(&Bs[wn * 32 + nj * 16 + (lane & 15)][kk * 32 + (lane >> 4) * 8]);
      #pragma unroll
      for (int mi = 0; mi < 2; mi++)
        acc[mi][nj] = __builtin_amdgcn_mfma_f32_16x16x32_bf16(af[mi], bfr, acc[mi][nj], 0, 0, 0);
    }
  }

  __syncthreads();
  #pragma unroll
  for (int mi = 0; mi < 2; mi++)
    #pragma unroll
    for (int nj = 0; nj < 2; nj++)
      #pragma unroll
      for (int q = 0; q < 4; q++){
        int row = wm * 32 + mi * 16 + (lane >> 4) * 4 + q;
        int col = wn * 32 + nj * 16 + (lane & 15);
        float g = gs_l[row][e];
        epi[row][col] = f2bf(g * tanhf(acc[mi][nj][q]));
      }
  __syncthreads();
  #pragma unroll
  for (int c = 0; c < 2; c++){
    int idx = c * 256 + tid;
    int row = idx >> 3;
    int col = (idx & 7) * 8;
    *(u16x8*)(wb + (size_t)(bm0 + row) * 256 + e * 64 + col) = *(const u16x8*)(&epi[row][col]);
  }
}

// ============ G3a: pure GEMM  Y = wb @ UfT -> ybf (bf16) ============
// 128x128 tile, 4 waves each 64x64, BK=32 (round-7 proven loop), u16x8 output.
__global__ __launch_bounds__(256, 4) void gemm_y_k(const unsigned short* __restrict__ A,
                                                   const unsigned short* __restrict__ BT,
                                                   unsigned short* __restrict__ ybf){
  const int bm0 = blockIdx.x * 128;
  const int bn0 = blockIdx.y * 128;
  const int tid = threadIdx.x;
  const int lane = tid & 63;
  const int wv = tid >> 6;
  const int wm = wv >> 1, wn = wv & 1;

  __shared__ __align__(16) char smraw[20480];
  unsigned short (*As)[40] = (unsigned short (*)[40])smraw;            // 10240 B
  unsigned short (*Bs)[40] = (unsigned short (*)[40])(smraw + 10240);  // 10240 B
  float (*epi)[132] = (float (*)[132])smraw;                           // 16896 B (union)

  f32x4 acc[4][4] = {};
  const int arow = tid >> 2;
  const int aseg = tid & 3;

  u16x8 ar0 = *(const u16x8*)(A + (size_t)(bm0 + arow) * 256 + aseg * 8);
  u16x8 ar1 = *(const u16x8*)(A + (size_t)(bm0 + arow + 64) * 256 + aseg * 8);
  u16x8 br0 = *(const u16x8*)(BT + (size_t)(bn0 + arow) * 256 + aseg * 8);
  u16x8 br1 = *(const u16x8*)(BT + (size_t)(bn0 + arow + 64) * 256 + aseg * 8);

  for (int k0 = 0; k0 < 256; k0 += 32){
    __syncthreads();
    *(u16x8*)(&As[arow][aseg * 8])      = ar0;
    *(u16x8*)(&As[arow + 64][aseg * 8]) = ar1;
    *(u16x8*)(&Bs[arow][aseg * 8])      = br0;
    *(u16x8*)(&Bs[arow + 64][aseg * 8]) = br1;
    __syncthreads();
    if (k0 + 32 < 256){
      ar0 = *(const u16x8*)(A + (size_t)(bm0 + arow) * 256 + k0 + 32 + aseg * 8);
      ar1 = *(const u16x8*)(A + (size_t)(bm0 + arow + 64) * 256 + k0 + 32 + aseg * 8);
      br0 = *(const u16x8*)(BT + (size_t)(bn0 + arow) * 256 + k0 + 32 + aseg * 8);
      br1 = *(const u16x8*)(BT + (size_t)(bn0 + arow + 64) * 256 + k0 + 32 + aseg * 8);
    }
    bf16x8 af[4];
    #pragma unroll
    for (int mi = 0; mi < 4; mi++)
      af[mi] = *reinterpret_cast<const bf16x8*>(&As[wm * 64 + mi * 16 + (lane & 15)][(lane >> 4) * 8]);
    #pragma unroll
    for (int nj = 0; nj < 4; nj++){
      bf16x8 bfr = *reinterpret_cast<const bf16x8*>(&Bs[wn * 64 + nj * 16 + (lane & 15)][(lane >> 4) * 8]);
      #pragma unroll
      for (int mi = 0; mi < 4; mi++)
        acc[mi][nj] = __builtin_amdgcn_mfma_f32_16x16x32_bf16(af[mi], bfr, acc[mi][nj], 0, 0, 0);
    }
  }

  // epilogue: 4 quarter-phases of 32 rows -> bf16, 16B/lane writes
  #pragma unroll
  for (int h = 0; h < 4; h++){
    __syncthreads();
    if (wm == (h >> 1)){
      const int mib = (h & 1) * 2;
      #pragma unroll
      for (int m2 = 0; m2 < 2; m2++)
        #pragma unroll
        for (int nj = 0; nj < 4; nj++)
          #pragma unroll
          for (int q = 0; q < 4; q++)
            epi[m2 * 16 + (lane >> 4) * 4 + q][wn * 64 + nj * 16 + (lane & 15)] = acc[mib + m2][nj][q];
    }
    __syncthreads();
    #pragma unroll
    for (int c = 0; c < 2; c++){
      int idx = c * 256 + tid;
      int r = idx >> 4;
      int col = (idx & 15) * 8;
      f32x4 v0 = *(const f32x4*)&epi[r][col];
      f32x4 v1 = *(const f32x4*)&epi[r][col + 4];
      u16x8 ov;
      #pragma unroll
      for (int j = 0; j < 4; j++){ ov[j] = f2bf(v0[j]); ov[4 + j] = f2bf(v1[j]); }
      *(u16x8*)(ybf + (size_t)(bm0 + h * 32 + r) * Dd + bn0 + col) = ov;
    }
  }
}

// ============ G3b: streaming combine  xn = xold + x0*(bias + y); next gate ============
// One wave per row (cast_gate's proven 6.3 TB/s pattern).
// MODE 0: xold = x0, write bf16 state + gate     (layer 0)
// MODE 1: xold = bf16 state RMW + gate           (layer 1)
// MODE 2: xold = bf16 state, write fp32 out      (layer 2, no gate)
template<int MODE, bool X0BF>
__global__ __launch_bounds__(256) void combine_k(const unsigned short* __restrict__ ybf,
                                                 const float* __restrict__ x0f,
                                                 const unsigned short* __restrict__ x0b,
                                                 unsigned short* __restrict__ xst,
                                                 const float* __restrict__ biasrow,
                                                 float* __restrict__ out,
                                                 const unsigned short* __restrict__ gw16,
                                                 float* __restrict__ gs){
  const int lane = threadIdx.x & 63;
  const int w = threadIdx.x >> 6;
  const int row = blockIdx.x * 4 + w;
  float s0 = 0.f, s1 = 0.f, s2 = 0.f, s3 = 0.f;
  #pragma unroll
  for (int c = 0; c < 4; c++){
    const int k = c * 512 + lane * 8;
    size_t o = (size_t)row * Dd + k;
    u16x8 yv = *(const u16x8*)(ybf + o);
    f32x4 b0 = *(const f32x4*)(biasrow + k);
    f32x4 b1 = *(const f32x4*)(biasrow + k + 4);
    float x0v[8];
    if constexpr (X0BF){
      u16x8 xv = *(const u16x8*)(x0b + o);
      #pragma unroll
      for (int j = 0; j < 8; j++) x0v[j] = bf2f(xv[j]);
    } else {
      f32x4 v0 = *(const f32x4*)(x0f + o);
      f32x4 v1 = *(const f32x4*)(x0f + o + 4);
      #pragma unroll
      for (int j = 0; j < 4; j++){ x0v[j] = v0[j]; x0v[4 + j] = v1[j]; }
    }
    float xo[8];
    if constexpr (MODE == 0){
      #pragma unroll
      for (int j = 0; j < 8; j++) xo[j] = x0v[j];
    } else {
      u16x8 sv = *(const u16x8*)(xst + o);
      #pragma unroll
      for (int j = 0; j < 8; j++) xo[j] = bf2f(sv[j]);
    }
    float xn[8];
    #pragma unroll
    for (int j = 0; j < 4; j++){
      xn[j]     = xo[j]     + x0v[j]     * (b0[j] + bf2f(yv[j]));
      xn[4 + j] = xo[4 + j] + x0v[4 + j] * (b1[j] + bf2f(yv[4 + j]));
    }
    if constexpr (MODE == 2){
      f32x4 o0, o1;
      #pragma unroll
      for (int j = 0; j < 4; j++){ o0[j] = xn[j]; o1[j] = xn[4 + j]; }
      *(f32x4*)(out + o) = o0;
      *(f32x4*)(out + o + 4) = o1;
    } else {
      u16x8 nv;
      #pragma unroll
      for (int j = 0; j < 8; j++) nv[j] = f2bf(xn[j]);
      *(u16x8*)(xst + o) = nv;
      u16x8 g0v = *(const u16x8*)(gw16 + 0 * Dd + k);
      u16x8 g1v = *(const u16x8*)(gw16 + 1 * Dd + k);
      u16x8 g2v = *(const u16x8*)(gw16 + 2 * Dd + k);
      u16x8 g3v = *(const u16x8*)(gw16 + 3 * Dd + k);
      #pragma unroll
      for (int j = 0; j < 8; j++){
        s0 += xn[j] * bf2f(g0v[j]);
        s1 += xn[j] * bf2f(g1v[j]);
        s2 += xn[j] * bf2f(g2v[j]);
        s3 += xn[j] * bf2f(g3v[j]);
      }
    }
  }
  if constexpr (MODE != 2){
    #pragma unroll
    for (int m = 1; m < 64; m <<= 1){
      s0 += __shfl_xor(s0, m, 64);
      s1 += __shfl_xor(s1, m, 64);
      s2 += __shfl_xor(s2, m, 64);
      s3 += __shfl_xor(s3, m, 64);
    }
    if (lane == 0){
      float mx = fmaxf(fmaxf(s0, s1), fmaxf(s2, s3));
      float e0 = __expf(s0 - mx), e1 = __expf(s1 - mx), e2 = __expf(s2 - mx), e3 = __expf(s3 - mx);
      float inv = 1.f / (e0 + e1 + e2 + e3);
      f32x4 g; g[0] = e0 * inv; g[1] = e1 * inv; g[2] = e2 * inv; g[3] = e3 * inv;
      *(f32x4*)(gs + (size_t)row * 4) = g;
    }
  }
}

extern "C" void kernel_launch(void* const* d_in, const int* in_sizes, int n_in,
                              void* d_out, int out_size, void* d_ws, size_t ws_size,
                              hipStream_t stream){
  (void)in_sizes; (void)n_in; (void)out_size;
  const float* inp  = (const float*)d_in[0];
  const float* U    = (const float*)d_in[1];
  const float* V    = (const float*)d_in[2];
  const float* C    = (const float*)d_in[3];
  const float* gw   = (const float*)d_in[4];
  const float* bias = (const float*)d_in[5];
  float* out = (float*)d_out;

  char* ws = (char*)d_ws;
  size_t o = 0;
  unsigned short* xb  = (unsigned short*)(ws + o); o += (size_t)Bb * Dd * 2;          // 33.55 MB (bf16 state)
  unsigned short* vxp = (unsigned short*)(ws + o); o += (size_t)4 * Bb * 256 * 2;     // 16.78 MB (bf16 partials)
  unsigned short* wb  = (unsigned short*)(ws + o); o += (size_t)Bb * 256 * 2;         //  4.19 MB
  unsigned short* ybf = (unsigned short*)(ws + o); o += (size_t)Bb * Dd * 2;          // 33.55 MB (bf16 Y)
  float*          gsb = (float*)(ws + o);          o += (size_t)Bb * 4 * 4;           //  0.13 MB
  unsigned short* vft = (unsigned short*)(ws + o); o += (size_t)Ll * 256 * Dd * 2;    //  3.15 MB
  unsigned short* uft = (unsigned short*)(ws + o); o += (size_t)Ll * Dd * 256 * 2;    //  3.15 MB
  unsigned short* cb16= (unsigned short*)(ws + o); o += (size_t)Ll * Ee * Rr * Rr * 2;//  0.10 MB
  unsigned short* g16 = (unsigned short*)(ws + o); o += (size_t)Ee * Dd * 2;          //  0.02 MB
  if (ws_size < o) return;
  unsigned short* x0b = nullptr;
  if (ws_size >= o + (size_t)Bb * Dd * 2){
    x0b = (unsigned short*)(ws + o); o += (size_t)Bb * Dd * 2;                        // 33.55 MB (bf16 x0)
  }
  const bool hx = (x0b != nullptr);

  prep_w_k<<<1024, 256, 0, stream>>>(U, V, C, gw, vft, uft, cb16, g16);
  if (hx) cast_gate_k<<<Bb / 4, 256, 0, stream>>>(inp, x0b, g16, gsb);
  else    gate_k<<<Bb / 4, 256, 0, stream>>>(inp, g16, gsb);

  for (int l = 0; l < Ll; l++){
    const unsigned short* vftl = vft + (size_t)l * 256 * Dd;
    const unsigned short* uftl = uft + (size_t)l * Dd * 256;
    const unsigned short* cbl  = cb16 + (size_t)l * Ee * Rr * Rr;
    const float* biasl = bias + (size_t)l * Dd;

    if (l == 0){
      if (hx) gemm1_k<false><<<dim3(Bb / 64, 2, 4), 256, 0, stream>>>(x0b, vftl, vxp);
      else    gemm1_k<true ><<<dim3(Bb / 64, 2, 4), 256, 0, stream>>>(inp, vftl, vxp);
    } else {
      gemm1_k<false><<<dim3(Bb / 64, 2, 4), 256, 0, stream>>>(xb, vftl, vxp);
    }
    gemm2_k<<<dim3(Bb / 64, Ee), 256, 0, stream>>>(vxp, cbl, gsb, wb);
    gemm_y_k<<<dim3(Bb / 128, Dd / 128), 256, 0, stream>>>(wb, uftl, ybf);

    dim3 gc(Bb / 4);
    if (l == 0){
      if (hx) combine_k<0, true ><<<gc, 256, 0, stream>>>(ybf, inp, x0b, xb, biasl, out, g16, gsb);
      else    combine_k<0, false><<<gc, 256, 0, stream>>>(ybf, inp, x0b, xb, biasl, out, g16, gsb);
    } else if (l == 1){
      if (hx) combine_k<1, true ><<<gc, 256, 0, stream>>>(ybf, inp, x0b, xb, biasl, out, g16, gsb);
      else    combine_k<1, false><<<gc, 256, 0, stream>>>(ybf, inp, x0b, xb, biasl, out, g16, gsb);
    } else {
      if (hx) combine_k<2, true ><<<gc, 256, 0, stream>>>(ybf, inp, x0b, xb, biasl, out, g16, gsb);
      else    combine_k<2, false><<<gc, 256, 0, stream>>>(ybf, inp, x0b, xb, biasl, out, g16, gsb);
    }
  }
}

// Round 12
// 209.351 us; speedup vs baseline: 1.0897x; 1.0897x over previous
//
#include <hip/hip_runtime.h>
#include <cmath>

#define Bb 8192
#define Dd 2048
#define Rr 64
#define Ee 4
#define Ll 3

typedef __bf16 bf16x8 __attribute__((ext_vector_type(8)));
typedef float f32x4 __attribute__((ext_vector_type(4)));
typedef unsigned short u16x8 __attribute__((ext_vector_type(8)));
typedef unsigned short u16x4 __attribute__((ext_vector_type(4)));

__device__ __forceinline__ unsigned short f2bf(float f){
  unsigned u = __builtin_bit_cast(unsigned, f);
  u += 0x7fffu + ((u >> 16) & 1u);
  return (unsigned short)(u >> 16);
}
__device__ __forceinline__ float bf2f(unsigned short h){
  return __builtin_bit_cast(float, ((unsigned)h) << 16);
}

// ---------------- prep: transpose/cast weights ----------------
__global__ __launch_bounds__(256) void prep_w_k(const float* __restrict__ U,
                                                const float* __restrict__ V,
                                                const float* __restrict__ C,
                                                const float* __restrict__ gw,
                                                unsigned short* __restrict__ VfT,
                                                unsigned short* __restrict__ UfT,
                                                unsigned short* __restrict__ cb16,
                                                unsigned short* __restrict__ gw16){
  const int NV = Ll * 256 * Dd;
  const int NU = Ll * Dd * 256;
  const int NC = Ll * Ee * Rr * Rr;
  const int NG = Ee * Dd;
  const int total = NV + NU + NC + NG;
  for (int idx = blockIdx.x * blockDim.x + threadIdx.x; idx < total; idx += gridDim.x * blockDim.x){
    if (idx < NV){
      int l = idx / (256 * Dd); int rem = idx - l * 256 * Dd;
      int n = rem / Dd, d = rem - n * Dd;
      int e = n >> 6, r = n & 63;
      VfT[idx] = f2bf(V[(((size_t)l * Ee + e) * Dd + d) * Rr + r]);
    } else if (idx < NV + NU){
      int j = idx - NV;
      int l = j / (Dd * 256); int rem = j - l * Dd * 256;
      int d = rem / 256, k = rem - d * 256;
      int e = k >> 6, s = k & 63;
      UfT[j] = f2bf(U[(((size_t)l * Ee + e) * Dd + d) * Rr + s]);
    } else if (idx < NV + NU + NC){
      int j = idx - NV - NU;
      cb16[j] = f2bf(C[j]);
    } else {
      int j = idx - NV - NU - NC;
      gw16[j] = f2bf(gw[j]);
    }
  }
}

// ---------------- fused cast + layer-0 gate: one wave per row ----------------
__global__ __launch_bounds__(256) void cast_gate_k(const float* __restrict__ x,
                                                   unsigned short* __restrict__ xb0,
                                                   const unsigned short* __restrict__ gw16,
                                                   float* __restrict__ gs){
  const int lane = threadIdx.x & 63;
  const int w = threadIdx.x >> 6;
  const int row = blockIdx.x * 4 + w;
  float s0 = 0.f, s1 = 0.f, s2 = 0.f, s3 = 0.f;
  #pragma unroll
  for (int c = 0; c < 4; c++){
    const int k = c * 512 + lane * 8;
    const float* xr = x + (size_t)row * Dd + k;
    f32x4 v0 = *(const f32x4*)xr;
    f32x4 v1 = *(const f32x4*)(xr + 4);
    float xf[8];
    u16x8 ob;
    #pragma unroll
    for (int u = 0; u < 4; u++){
      xf[u] = v0[u]; xf[4 + u] = v1[u];
      ob[u] = f2bf(v0[u]); ob[4 + u] = f2bf(v1[u]);
    }
    *(u16x8*)(xb0 + (size_t)row * Dd + k) = ob;
    u16x8 g0v = *(const u16x8*)(gw16 + 0 * Dd + k);
    u16x8 g1v = *(const u16x8*)(gw16 + 1 * Dd + k);
    u16x8 g2v = *(const u16x8*)(gw16 + 2 * Dd + k);
    u16x8 g3v = *(const u16x8*)(gw16 + 3 * Dd + k);
    #pragma unroll
    for (int u = 0; u < 8; u++){
      s0 += xf[u] * bf2f(g0v[u]);
      s1 += xf[u] * bf2f(g1v[u]);
      s2 += xf[u] * bf2f(g2v[u]);
      s3 += xf[u] * bf2f(g3v[u]);
    }
  }
  #pragma unroll
  for (int m = 1; m < 64; m <<= 1){
    s0 += __shfl_xor(s0, m, 64);
    s1 += __shfl_xor(s1, m, 64);
    s2 += __shfl_xor(s2, m, 64);
    s3 += __shfl_xor(s3, m, 64);
  }
  if (lane == 0){
    float mx = fmaxf(fmaxf(s0, s1), fmaxf(s2, s3));
    float e0 = __expf(s0 - mx), e1 = __expf(s1 - mx), e2 = __expf(s2 - mx), e3 = __expf(s3 - mx);
    float inv = 1.f / (e0 + e1 + e2 + e3);
    f32x4 g; g[0] = e0 * inv; g[1] = e1 * inv; g[2] = e2 * inv; g[3] = e3 * inv;
    *(f32x4*)(gs + (size_t)row * 4) = g;
  }
}

// ---------------- gate (fallback, fp32 input): one wave per row ----------------
__global__ __launch_bounds__(256) void gate_k(const float* __restrict__ xv,
                                              const unsigned short* __restrict__ gw16,
                                              float* __restrict__ gs){
  const int lane = threadIdx.x & 63;
  const int w = threadIdx.x >> 6;
  const int row = blockIdx.x * 4 + w;
  float s0 = 0.f, s1 = 0.f, s2 = 0.f, s3 = 0.f;
  #pragma unroll
  for (int c = 0; c < 4; c++){
    const int k = c * 512 + lane * 8;
    const float* xr = xv + (size_t)row * Dd + k;
    f32x4 v0 = *(const f32x4*)xr;
    f32x4 v1 = *(const f32x4*)(xr + 4);
    float xf[8];
    #pragma unroll
    for (int u = 0; u < 4; u++){ xf[u] = v0[u]; xf[4 + u] = v1[u]; }
    u16x8 g0v = *(const u16x8*)(gw16 + 0 * Dd + k);
    u16x8 g1v = *(const u16x8*)(gw16 + 1 * Dd + k);
    u16x8 g2v = *(const u16x8*)(gw16 + 2 * Dd + k);
    u16x8 g3v = *(const u16x8*)(gw16 + 3 * Dd + k);
    #pragma unroll
    for (int u = 0; u < 8; u++){
      s0 += xf[u] * bf2f(g0v[u]);
      s1 += xf[u] * bf2f(g1v[u]);
      s2 += xf[u] * bf2f(g2v[u]);
      s3 += xf[u] * bf2f(g3v[u]);
    }
  }
  #pragma unroll
  for (int m = 1; m < 64; m <<= 1){
    s0 += __shfl_xor(s0, m, 64);
    s1 += __shfl_xor(s1, m, 64);
    s2 += __shfl_xor(s2, m, 64);
    s3 += __shfl_xor(s3, m, 64);
  }
  if (lane == 0){
    float mx = fmaxf(fmaxf(s0, s1), fmaxf(s2, s3));
    float e0 = __expf(s0 - mx), e1 = __expf(s1 - mx), e2 = __expf(s2 - mx), e3 = __expf(s3 - mx);
    float inv = 1.f / (e0 + e1 + e2 + e3);
    f32x4 g; g[0] = e0 * inv; g[1] = e1 * inv; g[2] = e2 * inv; g[3] = e3 * inv;
    *(f32x4*)(gs + (size_t)row * 4) = g;
  }
}

// ============ G1: T = X @ VfT, split-K=4, bf16 partials ============
// 128x128 tile (gemm_y structure), 4 waves each 64x64, BK=32, reg-prefetch.
// grid (Bb/128, 2, 4). 16 K-iters per block (K-chunk 512).
template<bool AF32>
__global__ __launch_bounds__(256) void gemm1_k(const void* __restrict__ Av,
                                               const unsigned short* __restrict__ BT,
                                               unsigned short* __restrict__ vxp){
  const int bm0 = blockIdx.x * 128;
  const int bn0 = blockIdx.y * 128;
  const int z   = blockIdx.z;
  const int kc0 = z * 512;
  const int tid = threadIdx.x;
  const int lane = tid & 63;
  const int wv = tid >> 6;
  const int wm = wv >> 1, wn = wv & 1;

  __shared__ __align__(16) char smraw[20480];
  unsigned short (*As)[40] = (unsigned short (*)[40])smraw;            // 10240 B
  unsigned short (*Bs)[40] = (unsigned short (*)[40])(smraw + 10240);  // 10240 B
  float (*epi)[132] = (float (*)[132])smraw;                           // 16896 B (union)

  f32x4 acc[4][4] = {};
  const int arow = tid >> 2;   // 0..63 (covers rows arow, arow+64)
  const int aseg = tid & 3;    // 8 elems each

  const float* Af = (const float*)Av;
  const unsigned short* Ab = (const unsigned short*)Av;

  f32x4 a4[4]; u16x8 ar0, ar1;
  u16x8 br0, br1;
  if constexpr (AF32){
    a4[0] = *(const f32x4*)(Af + (size_t)(bm0 + arow) * Dd + kc0 + aseg * 8);
    a4[1] = *(const f32x4*)(Af + (size_t)(bm0 + arow) * Dd + kc0 + aseg * 8 + 4);
    a4[2] = *(const f32x4*)(Af + (size_t)(bm0 + arow + 64) * Dd + kc0 + aseg * 8);
    a4[3] = *(const f32x4*)(Af + (size_t)(bm0 + arow + 64) * Dd + kc0 + aseg * 8 + 4);
  } else {
    ar0 = *(const u16x8*)(Ab + (size_t)(bm0 + arow) * Dd + kc0 + aseg * 8);
    ar1 = *(const u16x8*)(Ab + (size_t)(bm0 + arow + 64) * Dd + kc0 + aseg * 8);
  }
  br0 = *(const u16x8*)(BT + (size_t)(bn0 + arow) * Dd + kc0 + aseg * 8);
  br1 = *(const u16x8*)(BT + (size_t)(bn0 + arow + 64) * Dd + kc0 + aseg * 8);

  for (int k0 = kc0; k0 < kc0 + 512; k0 += 32){
    __syncthreads();
    if constexpr (AF32){
      u16x8 av0, av1;
      #pragma unroll
      for (int j = 0; j < 4; j++){
        av0[j] = f2bf(a4[0][j]); av0[4 + j] = f2bf(a4[1][j]);
        av1[j] = f2bf(a4[2][j]); av1[4 + j] = f2bf(a4[3][j]);
      }
      *(u16x8*)(&As[arow][aseg * 8])      = av0;
      *(u16x8*)(&As[arow + 64][aseg * 8]) = av1;
    } else {
      *(u16x8*)(&As[arow][aseg * 8])      = ar0;
      *(u16x8*)(&As[arow + 64][aseg * 8]) = ar1;
    }
    *(u16x8*)(&Bs[arow][aseg * 8])      = br0;
    *(u16x8*)(&Bs[arow + 64][aseg * 8]) = br1;
    __syncthreads();

    int kn = k0 + 32;
    if (kn < kc0 + 512){
      if constexpr (AF32){
        a4[0] = *(const f32x4*)(Af + (size_t)(bm0 + arow) * Dd + kn + aseg * 8);
        a4[1] = *(const f32x4*)(Af + (size_t)(bm0 + arow) * Dd + kn + aseg * 8 + 4);
        a4[2] = *(const f32x4*)(Af + (size_t)(bm0 + arow + 64) * Dd + kn + aseg * 8);
        a4[3] = *(const f32x4*)(Af + (size_t)(bm0 + arow + 64) * Dd + kn + aseg * 8 + 4);
      } else {
        ar0 = *(const u16x8*)(Ab + (size_t)(bm0 + arow) * Dd + kn + aseg * 8);
        ar1 = *(const u16x8*)(Ab + (size_t)(bm0 + arow + 64) * Dd + kn + aseg * 8);
      }
      br0 = *(const u16x8*)(BT + (size_t)(bn0 + arow) * Dd + kn + aseg * 8);
      br1 = *(const u16x8*)(BT + (size_t)(bn0 + arow + 64) * Dd + kn + aseg * 8);
    }

    bf16x8 af[4];
    #pragma unroll
    for (int mi = 0; mi < 4; mi++)
      af[mi] = *reinterpret_cast<const bf16x8*>(&As[wm * 64 + mi * 16 + (lane & 15)][(lane >> 4) * 8]);
    #pragma unroll
    for (int nj = 0; nj < 4; nj++){
      bf16x8 bfr = *reinterpret_cast<const bf16x8*>(&Bs[wn * 64 + nj * 16 + (lane & 15)][(lane >> 4) * 8]);
      #pragma unroll
      for (int mi = 0; mi < 4; mi++)
        acc[mi][nj] = __builtin_amdgcn_mfma_f32_16x16x32_bf16(af[mi], bfr, acc[mi][nj], 0, 0, 0);
    }
  }

  // epilogue: 4 quarter-phases of 32 rows -> bf16 partials (z-plane)
  unsigned short* outz = vxp + (size_t)z * Bb * 256;
  #pragma unroll
  for (int h = 0; h < 4; h++){
    __syncthreads();
    if (wm == (h >> 1)){
      const int mib = (h & 1) * 2;
      #pragma unroll
      for (int m2 = 0; m2 < 2; m2++)
        #pragma unroll
        for (int nj = 0; nj < 4; nj++)
          #pragma unroll
          for (int q = 0; q < 4; q++)
            epi[m2 * 16 + (lane >> 4) * 4 + q][wn * 64 + nj * 16 + (lane & 15)] = acc[mib + m2][nj][q];
    }
    __syncthreads();
    #pragma unroll
    for (int c = 0; c < 2; c++){
      int idx = c * 256 + tid;
      int r = idx >> 4;
      int col = (idx & 15) * 8;
      f32x4 v0 = *(const f32x4*)&epi[r][col];
      f32x4 v1 = *(const f32x4*)&epi[r][col + 4];
      u16x8 ov;
      #pragma unroll
      for (int j = 0; j < 4; j++){ ov[j] = f2bf(v0[j]); ov[4 + j] = f2bf(v1[j]); }
      *(u16x8*)(outz + (size_t)(bm0 + h * 32 + r) * 256 + bn0 + col) = ov;
    }
  }
}

// ============ G2: block-diag C; sums bf16 partials; softmax from plog (l>=1) ============
template<bool FROMPLOG>
__global__ __launch_bounds__(256) void gemm2_k(const unsigned short* __restrict__ vxp,
                                               const unsigned short* __restrict__ cb,
                                               const float* __restrict__ gsb,
                                               const float* __restrict__ plog,
                                               unsigned short* __restrict__ wb){
  const int bm0 = blockIdx.x * 64;
  const int e   = blockIdx.y;
  const int tid = threadIdx.x;
  const int lane = tid & 63;
  const int wv = tid >> 6;
  const int wm = wv >> 1, wn = wv & 1;

  __shared__ __align__(16) char smraw[19456];
  unsigned short (*As)[72] = (unsigned short (*)[72])smraw;            // 9216
  unsigned short (*Bs)[72] = (unsigned short (*)[72])(smraw + 9216);   // 9216
  float (*gs_l)[4] = (float (*)[4])(smraw + 18432);                    // 1024
  unsigned short (*epi)[72] = (unsigned short (*)[72])smraw;           // union As

  if constexpr (FROMPLOG){
    int r = tid >> 2, q = tid & 3;
    f32x4 s = {0.f, 0.f, 0.f, 0.f};
    #pragma unroll
    for (int ci = 0; ci < 4; ci++)
      s += *(const f32x4*)(plog + ((size_t)(q * 4 + ci) * Bb + bm0 + r) * 4);
    #pragma unroll
    for (int j = 0; j < 4; j++){
      s[j] += __shfl_xor(s[j], 1, 64);
      s[j] += __shfl_xor(s[j], 2, 64);
    }
    if (q == 0){
      float mx = fmaxf(fmaxf(s[0], s[1]), fmaxf(s[2], s[3]));
      float e0 = __expf(s[0] - mx), e1 = __expf(s[1] - mx), e2 = __expf(s[2] - mx), e3 = __expf(s[3] - mx);
      float inv = 1.f / (e0 + e1 + e2 + e3);
      f32x4 g; g[0] = e0 * inv; g[1] = e1 * inv; g[2] = e2 * inv; g[3] = e3 * inv;
      *(f32x4*)&gs_l[r][0] = g;
    }
  } else {
    if (tid < 64) *(f32x4*)&gs_l[tid][0] = *(const f32x4*)(gsb + (size_t)(bm0 + tid) * 4);
  }

  const int arow = tid >> 2;
  const int aseg = tid & 3;

  float tv[16];
  #pragma unroll
  for (int j = 0; j < 16; j++) tv[j] = 0.f;
  #pragma unroll
  for (int z = 0; z < 4; z++){
    const unsigned short* vz = vxp + ((size_t)z * Bb + bm0 + arow) * 256 + e * 64 + aseg * 16;
    u16x8 p0 = *(const u16x8*)vz;
    u16x8 p1 = *(const u16x8*)(vz + 8);
    #pragma unroll
    for (int j = 0; j < 8; j++){ tv[j] += bf2f(p0[j]); tv[8 + j] += bf2f(p1[j]); }
  }
  u16x8 av0, av1;
  #pragma unroll
  for (int j = 0; j < 4; j++){
    av0[j] = f2bf(tanhf(tv[j]));     av0[4 + j] = f2bf(tanhf(tv[4 + j]));
    av1[j] = f2bf(tanhf(tv[8 + j])); av1[4 + j] = f2bf(tanhf(tv[12 + j]));
  }
  *(u16x8*)(&As[arow][aseg * 16]) = av0;
  *(u16x8*)(&As[arow][aseg * 16 + 8]) = av1;
  *(u16x8*)(&Bs[arow][aseg * 16])     = *(const u16x8*)(cb + e * 4096 + arow * 64 + aseg * 16);
  *(u16x8*)(&Bs[arow][aseg * 16 + 8]) = *(const u16x8*)(cb + e * 4096 + arow * 64 + aseg * 16 + 8);
  __syncthreads();

  f32x4 acc[2][2] = {};
  #pragma unroll
  for (int kk = 0; kk < 2; kk++){
    bf16x8 af[2];
    #pragma unroll
    for (int mi = 0; mi < 2; mi++)
      af[mi] = *reinterpret_cast<const bf16x8*>(&As[wm * 32 + mi * 16 + (lane & 15)][kk * 32 + (lane >> 4) * 8]);
    #pragma unroll
    for (int nj = 0; nj < 2; nj++){
      bf16x8 bfr = *reinterpret_cast<const bf16x8*>(&Bs[wn * 32 + nj * 16 + (lane & 15)][kk * 32 + (lane >> 4) * 8]);
      #pragma unroll
      for (int mi = 0; mi < 2; mi++)
        acc[mi][nj] = __builtin_amdgcn_mfma_f32_16x16x32_bf16(af[mi], bfr, acc[mi][nj], 0, 0, 0);
    }
  }

  __syncthreads();
  #pragma unroll
  for (int mi = 0; mi < 2; mi++)
    #pragma unroll
    for (int nj = 0; nj < 2; nj++)
      #pragma unroll
      for (int q = 0; q < 4; q++){
        int row = wm * 32 + mi * 16 + (lane >> 4) * 4 + q;
        int col = wn * 32 + nj * 16 + (lane & 15);
        float g = gs_l[row][e];
        epi[row][col] = f2bf(g * tanhf(acc[mi][nj][q]));
      }
  __syncthreads();
  #pragma unroll
  for (int c = 0; c < 2; c++){
    int idx = c * 256 + tid;
    int row = idx >> 3;
    int col = (idx & 7) * 8;
    *(u16x8*)(wb + (size_t)(bm0 + row) * 256 + e * 64 + col) = *(const u16x8*)(&epi[row][col]);
  }
}

// ============ G3: Y = wb @ UfT; x_new = xold + x0*(bias + Y); fused next-gate ============
// 128x128 tile, 4 waves each 64x64, BK=32, inline epilogue (round-7 proven, 38us).
template<int MODE, bool X0BF>
__global__ __launch_bounds__(256, 4) void gemm3_k(const unsigned short* __restrict__ A,
                                                  const unsigned short* __restrict__ BT,
                                                  const float* __restrict__ x0f,
                                                  const unsigned short* __restrict__ x0b,
                                                  unsigned short* __restrict__ xst,
                                                  const float* __restrict__ biasrow,
                                                  float* __restrict__ out,
                                                  const unsigned short* __restrict__ gw16,
                                                  float* __restrict__ plog){
  const int bm0 = blockIdx.x * 128;
  const int bn0 = blockIdx.y * 128;
  const int tid = threadIdx.x;
  const int lane = tid & 63;
  const int wv = tid >> 6;
  const int wm = wv >> 1, wn = wv & 1;

  __shared__ __align__(16) char smraw[20480];
  unsigned short (*As)[40] = (unsigned short (*)[40])smraw;            // 10240 B
  unsigned short (*Bs)[40] = (unsigned short (*)[40])(smraw + 10240);  // 10240 B
  float (*epi)[132] = (float (*)[132])smraw;                           // 16896 B

  f32x4 acc[4][4] = {};
  const int arow = tid >> 2;
  const int aseg = tid & 3;

  u16x8 ar0 = *(const u16x8*)(A + (size_t)(bm0 + arow) * 256 + aseg * 8);
  u16x8 ar1 = *(const u16x8*)(A + (size_t)(bm0 + arow + 64) * 256 + aseg * 8);
  u16x8 br0 = *(const u16x8*)(BT + (size_t)(bn0 + arow) * 256 + aseg * 8);
  u16x8 br1 = *(const u16x8*)(BT + (size_t)(bn0 + arow + 64) * 256 + aseg * 8);

  for (int k0 = 0; k0 < 256; k0 += 32){
    __syncthreads();
    *(u16x8*)(&As[arow][aseg * 8])      = ar0;
    *(u16x8*)(&As[arow + 64][aseg * 8]) = ar1;
    *(u16x8*)(&Bs[arow][aseg * 8])      = br0;
    *(u16x8*)(&Bs[arow + 64][aseg * 8]) = br1;
    __syncthreads();
    if (k0 + 32 < 256){
      ar0 = *(const u16x8*)(A + (size_t)(bm0 + arow) * 256 + k0 + 32 + aseg * 8);
      ar1 = *(const u16x8*)(A + (size_t)(bm0 + arow + 64) * 256 + k0 + 32 + aseg * 8);
      br0 = *(const u16x8*)(BT + (size_t)(bn0 + arow) * 256 + k0 + 32 + aseg * 8);
      br1 = *(const u16x8*)(BT + (size_t)(bn0 + arow + 64) * 256 + k0 + 32 + aseg * 8);
    }
    bf16x8 af[4];
    #pragma unroll
    for (int mi = 0; mi < 4; mi++)
      af[mi] = *reinterpret_cast<const bf16x8*>(&As[wm * 64 + mi * 16 + (lane & 15)][(lane >> 4) * 8]);
    #pragma unroll
    for (int nj = 0; nj < 4; nj++){
      bf16x8 bfr = *reinterpret_cast<const bf16x8*>(&Bs[wn * 64 + nj * 16 + (lane & 15)][(lane >> 4) * 8]);
      #pragma unroll
      for (int mi = 0; mi < 4; mi++)
        acc[mi][nj] = __builtin_amdgcn_mfma_f32_16x16x32_bf16(af[mi], bfr, acc[mi][nj], 0, 0, 0);
    }
  }

  // epilogue: 4 quarter-phases of 32 rows each through LDS, inline operand loads
  #pragma unroll
  for (int h = 0; h < 4; h++){
    __syncthreads();
    if (wm == (h >> 1)){
      const int mib = (h & 1) * 2;
      #pragma unroll
      for (int m2 = 0; m2 < 2; m2++)
        #pragma unroll
        for (int nj = 0; nj < 4; nj++)
          #pragma unroll
          for (int q = 0; q < 4; q++)
            epi[m2 * 16 + (lane >> 4) * 4 + q][wn * 64 + nj * 16 + (lane & 15)] = acc[mib + m2][nj][q];
    }
    __syncthreads();
    #pragma unroll
    for (int c = 0; c < 4; c++){
      int idx = c * 256 + tid;
      int r = idx >> 5;
      int col = (idx & 31) * 4;
      int row = bm0 + h * 32 + r;
      size_t o = (size_t)row * Dd + bn0 + col;
      f32x4 y = *(const f32x4*)&epi[r][col];
      f32x4 bv = *(const f32x4*)(biasrow + bn0 + col);
      f32x4 x0v;
      if constexpr (X0BF){
        u16x4 xv = *(const u16x4*)(x0b + o);
        #pragma unroll
        for (int j = 0; j < 4; j++) x0v[j] = bf2f(xv[j]);
      } else {
        x0v = *(const f32x4*)(x0f + o);
      }
      f32x4 xo;
      if constexpr (MODE == 0){
        xo = x0v;
      } else {
        u16x4 xv = *(const u16x4*)(xst + o);
        #pragma unroll
        for (int j = 0; j < 4; j++) xo[j] = bf2f(xv[j]);
      }
      f32x4 xn;
      #pragma unroll
      for (int j = 0; j < 4; j++) xn[j] = xo[j] + x0v[j] * (bv[j] + y[j]);
      if constexpr (MODE == 2){
        *(f32x4*)(out + o) = xn;
      } else {
        u16x4 xnb;
        #pragma unroll
        for (int j = 0; j < 4; j++) xnb[j] = f2bf(xn[j]);
        *(u16x4*)(xst + o) = xnb;
      }
      if constexpr (MODE != 2){
        float s[4];
        #pragma unroll
        for (int e = 0; e < 4; e++){
          u16x4 gv = *(const u16x4*)(gw16 + (size_t)e * Dd + bn0 + col);
          s[e] = xn[0] * bf2f(gv[0]) + xn[1] * bf2f(gv[1])
               + xn[2] * bf2f(gv[2]) + xn[3] * bf2f(gv[3]);
        }
        #pragma unroll
        for (int m = 1; m < 32; m <<= 1)
          #pragma unroll
          for (int e = 0; e < 4; e++) s[e] += __shfl_xor(s[e], m, 64);
        if ((tid & 31) == 0){
          f32x4 pv; pv[0] = s[0]; pv[1] = s[1]; pv[2] = s[2]; pv[3] = s[3];
          *(f32x4*)(plog + ((size_t)blockIdx.y * Bb + row) * 4) = pv;
        }
      }
    }
  }
}

extern "C" void kernel_launch(void* const* d_in, const int* in_sizes, int n_in,
                              void* d_out, int out_size, void* d_ws, size_t ws_size,
                              hipStream_t stream){
  (void)in_sizes; (void)n_in; (void)out_size;
  const float* inp  = (const float*)d_in[0];
  const float* U    = (const float*)d_in[1];
  const float* V    = (const float*)d_in[2];
  const float* C    = (const float*)d_in[3];
  const float* gw   = (const float*)d_in[4];
  const float* bias = (const float*)d_in[5];
  float* out = (float*)d_out;

  char* ws = (char*)d_ws;
  size_t o = 0;
  unsigned short* xb  = (unsigned short*)(ws + o); o += (size_t)Bb * Dd * 2;          // 33.55 MB (bf16 state)
  unsigned short* vxp = (unsigned short*)(ws + o); o += (size_t)4 * Bb * 256 * 2;     // 16.78 MB (bf16 partials)
  unsigned short* wb  = (unsigned short*)(ws + o); o += (size_t)Bb * 256 * 2;         //  4.19 MB
  float*          gsb = (float*)(ws + o);          o += (size_t)Bb * 4 * 4;           //  0.13 MB
  float*          plog= (float*)(ws + o);          o += (size_t)16 * Bb * 4 * 4;      //  2.10 MB
  unsigned short* vft = (unsigned short*)(ws + o); o += (size_t)Ll * 256 * Dd * 2;    //  3.15 MB
  unsigned short* uft = (unsigned short*)(ws + o); o += (size_t)Ll * Dd * 256 * 2;    //  3.15 MB
  unsigned short* cb16= (unsigned short*)(ws + o); o += (size_t)Ll * Ee * Rr * Rr * 2;//  0.10 MB
  unsigned short* g16 = (unsigned short*)(ws + o); o += (size_t)Ee * Dd * 2;          //  0.02 MB
  if (ws_size < o) return;
  unsigned short* x0b = nullptr;
  if (ws_size >= o + (size_t)Bb * Dd * 2){
    x0b = (unsigned short*)(ws + o); o += (size_t)Bb * Dd * 2;                        // 33.55 MB (bf16 x0)
  }
  const bool hx = (x0b != nullptr);

  prep_w_k<<<1024, 256, 0, stream>>>(U, V, C, gw, vft, uft, cb16, g16);
  if (hx) cast_gate_k<<<Bb / 4, 256, 0, stream>>>(inp, x0b, g16, gsb);

  for (int l = 0; l < Ll; l++){
    const unsigned short* vftl = vft + (size_t)l * 256 * Dd;
    const unsigned short* uftl = uft + (size_t)l * Dd * 256;
    const unsigned short* cbl  = cb16 + (size_t)l * Ee * Rr * Rr;
    const float* biasl = bias + (size_t)l * Dd;

    if (l == 0){
      if (hx){
        gemm1_k<false><<<dim3(Bb / 128, 2, 4), 256, 0, stream>>>(x0b, vftl, vxp);
      } else {
        gate_k<<<Bb / 4, 256, 0, stream>>>(inp, g16, gsb);
        gemm1_k<true><<<dim3(Bb / 128, 2, 4), 256, 0, stream>>>(inp, vftl, vxp);
      }
      gemm2_k<false><<<dim3(Bb / 64, Ee), 256, 0, stream>>>(vxp, cbl, gsb, plog, wb);
    } else {
      gemm1_k<false><<<dim3(Bb / 128, 2, 4), 256, 0, stream>>>(xb, vftl, vxp);
      gemm2_k<true><<<dim3(Bb / 64, Ee), 256, 0, stream>>>(vxp, cbl, gsb, plog, wb);
    }

    dim3 g3(Bb / 128, Dd / 128);
    if (l == 0){
      if (hx) gemm3_k<0, true ><<<g3, 256, 0, stream>>>(wb, uftl, inp, x0b, xb, biasl, out, g16, plog);
      else    gemm3_k<0, false><<<g3, 256, 0, stream>>>(wb, uftl, inp, x0b, xb, biasl, out, g16, plog);
    } else if (l == 1){
      if (hx) gemm3_k<1, true ><<<g3, 256, 0, stream>>>(wb, uftl, inp, x0b, xb, biasl, out, g16, plog);
      else    gemm3_k<1, false><<<g3, 256, 0, stream>>>(wb, uftl, inp, x0b, xb, biasl, out, g16, plog);
    } else {
      if (hx) gemm3_k<2, true ><<<g3, 256, 0, stream>>>(wb, uftl, inp, x0b, xb, biasl, out, g16, plog);
      else    gemm3_k<2, false><<<g3, 256, 0, stream>>>(wb, uftl, inp, x0b, xb, biasl, out, g16, plog);
    }
  }
}

// Round 13
// 208.581 us; speedup vs baseline: 1.0938x; 1.0037x over previous
//
#include <hip/hip_runtime.h>
#include <cmath>

#define Bb 8192
#define Dd 2048
#define Rr 64
#define Ee 4
#define Ll 3

typedef __bf16 bf16x8 __attribute__((ext_vector_type(8)));
typedef float f32x4 __attribute__((ext_vector_type(4)));
typedef unsigned short u16x8 __attribute__((ext_vector_type(8)));
typedef unsigned short u16x4 __attribute__((ext_vector_type(4)));

__device__ __forceinline__ unsigned short f2bf(float f){
  unsigned u = __builtin_bit_cast(unsigned, f);
  u += 0x7fffu + ((u >> 16) & 1u);
  return (unsigned short)(u >> 16);
}
__device__ __forceinline__ float bf2f(unsigned short h){
  return __builtin_bit_cast(float, ((unsigned)h) << 16);
}

// ---------------- prep: transpose/cast weights ----------------
__global__ __launch_bounds__(256) void prep_w_k(const float* __restrict__ U,
                                                const float* __restrict__ V,
                                                const float* __restrict__ C,
                                                const float* __restrict__ gw,
                                                unsigned short* __restrict__ VfT,
                                                unsigned short* __restrict__ UfT,
                                                unsigned short* __restrict__ cb16,
                                                unsigned short* __restrict__ gw16){
  const int NV = Ll * 256 * Dd;
  const int NU = Ll * Dd * 256;
  const int NC = Ll * Ee * Rr * Rr;
  const int NG = Ee * Dd;
  const int total = NV + NU + NC + NG;
  for (int idx = blockIdx.x * blockDim.x + threadIdx.x; idx < total; idx += gridDim.x * blockDim.x){
    if (idx < NV){
      int l = idx / (256 * Dd); int rem = idx - l * 256 * Dd;
      int n = rem / Dd, d = rem - n * Dd;
      int e = n >> 6, r = n & 63;
      VfT[idx] = f2bf(V[(((size_t)l * Ee + e) * Dd + d) * Rr + r]);
    } else if (idx < NV + NU){
      int j = idx - NV;
      int l = j / (Dd * 256); int rem = j - l * Dd * 256;
      int d = rem / 256, k = rem - d * 256;
      int e = k >> 6, s = k & 63;
      UfT[j] = f2bf(U[(((size_t)l * Ee + e) * Dd + d) * Rr + s]);
    } else if (idx < NV + NU + NC){
      int j = idx - NV - NU;
      cb16[j] = f2bf(C[j]);
    } else {
      int j = idx - NV - NU - NC;
      gw16[j] = f2bf(gw[j]);
    }
  }
}

// ---------------- gate (fallback, fp32 input): one wave per row ----------------
__global__ __launch_bounds__(256) void gate_k(const float* __restrict__ xv,
                                              const unsigned short* __restrict__ gw16,
                                              float* __restrict__ gs){
  const int lane = threadIdx.x & 63;
  const int w = threadIdx.x >> 6;
  const int row = blockIdx.x * 4 + w;
  float s0 = 0.f, s1 = 0.f, s2 = 0.f, s3 = 0.f;
  #pragma unroll
  for (int c = 0; c < 4; c++){
    const int k = c * 512 + lane * 8;
    const float* xr = xv + (size_t)row * Dd + k;
    f32x4 v0 = *(const f32x4*)xr;
    f32x4 v1 = *(const f32x4*)(xr + 4);
    float xf[8];
    #pragma unroll
    for (int u = 0; u < 4; u++){ xf[u] = v0[u]; xf[4 + u] = v1[u]; }
    u16x8 g0v = *(const u16x8*)(gw16 + 0 * Dd + k);
    u16x8 g1v = *(const u16x8*)(gw16 + 1 * Dd + k);
    u16x8 g2v = *(const u16x8*)(gw16 + 2 * Dd + k);
    u16x8 g3v = *(const u16x8*)(gw16 + 3 * Dd + k);
    #pragma unroll
    for (int u = 0; u < 8; u++){
      s0 += xf[u] * bf2f(g0v[u]);
      s1 += xf[u] * bf2f(g1v[u]);
      s2 += xf[u] * bf2f(g2v[u]);
      s3 += xf[u] * bf2f(g3v[u]);
    }
  }
  #pragma unroll
  for (int m = 1; m < 64; m <<= 1){
    s0 += __shfl_xor(s0, m, 64);
    s1 += __shfl_xor(s1, m, 64);
    s2 += __shfl_xor(s2, m, 64);
    s3 += __shfl_xor(s3, m, 64);
  }
  if (lane == 0){
    float mx = fmaxf(fmaxf(s0, s1), fmaxf(s2, s3));
    float e0 = __expf(s0 - mx), e1 = __expf(s1 - mx), e2 = __expf(s2 - mx), e3 = __expf(s3 - mx);
    float inv = 1.f / (e0 + e1 + e2 + e3);
    f32x4 g; g[0] = e0 * inv; g[1] = e1 * inv; g[2] = e2 * inv; g[3] = e3 * inv;
    *(f32x4*)(gs + (size_t)row * 4) = g;
  }
}

// ============ G1: T = X @ VfT, split-K=4, bf16 partials ============
// 128x128 tile, 4 waves each 64x64, BK=32, reg-prefetch. grid (Bb/128, 2, 4).
// M1==0: A is bf16 (steady-state layers)
// M1==1: A is fp32 inp; bn==0 blocks ALSO write x0b (bf16 cast) and per-z
//        partial gate logits -> plog[z]   (fused cast+gate, layer 0)
// M1==2: A is fp32 inp, plain (fallback)
template<int M1>
__global__ __launch_bounds__(256) void gemm1_k(const void* __restrict__ Av,
                                               const unsigned short* __restrict__ BT,
                                               unsigned short* __restrict__ vxp,
                                               unsigned short* __restrict__ x0b,
                                               const unsigned short* __restrict__ gw16,
                                               float* __restrict__ plog){
  const int bm0 = blockIdx.x * 128;
  const int bn0 = blockIdx.y * 128;
  const int z   = blockIdx.z;
  const int kc0 = z * 512;
  const int tid = threadIdx.x;
  const int lane = tid & 63;
  const int wv = tid >> 6;
  const int wm = wv >> 1, wn = wv & 1;

  __shared__ __align__(16) char smraw[20480];
  unsigned short (*As)[40] = (unsigned short (*)[40])smraw;            // 10240 B
  unsigned short (*Bs)[40] = (unsigned short (*)[40])(smraw + 10240);  // 10240 B
  float (*epi)[132] = (float (*)[132])smraw;                           // 16896 B (union)

  f32x4 acc[4][4] = {};
  const int arow = tid >> 2;   // 0..63 (covers rows arow, arow+64)
  const int aseg = tid & 3;    // 8 elems each

  const float* Af = (const float*)Av;
  const unsigned short* Ab = (const unsigned short*)Av;
  const bool dog = (M1 == 1) && (bn0 == 0);

  float sg0[4] = {0.f, 0.f, 0.f, 0.f};   // gate partials, row arow
  float sg1[4] = {0.f, 0.f, 0.f, 0.f};   // row arow+64

  f32x4 a4[4]; u16x8 ar0, ar1;
  u16x8 br0, br1;
  if constexpr (M1 != 0){
    a4[0] = *(const f32x4*)(Af + (size_t)(bm0 + arow) * Dd + kc0 + aseg * 8);
    a4[1] = *(const f32x4*)(Af + (size_t)(bm0 + arow) * Dd + kc0 + aseg * 8 + 4);
    a4[2] = *(const f32x4*)(Af + (size_t)(bm0 + arow + 64) * Dd + kc0 + aseg * 8);
    a4[3] = *(const f32x4*)(Af + (size_t)(bm0 + arow + 64) * Dd + kc0 + aseg * 8 + 4);
  } else {
    ar0 = *(const u16x8*)(Ab + (size_t)(bm0 + arow) * Dd + kc0 + aseg * 8);
    ar1 = *(const u16x8*)(Ab + (size_t)(bm0 + arow + 64) * Dd + kc0 + aseg * 8);
  }
  br0 = *(const u16x8*)(BT + (size_t)(bn0 + arow) * Dd + kc0 + aseg * 8);
  br1 = *(const u16x8*)(BT + (size_t)(bn0 + arow + 64) * Dd + kc0 + aseg * 8);

  for (int k0 = kc0; k0 < kc0 + 512; k0 += 32){
    __syncthreads();
    if constexpr (M1 != 0){
      u16x8 av0, av1;
      #pragma unroll
      for (int j = 0; j < 4; j++){
        av0[j] = f2bf(a4[0][j]); av0[4 + j] = f2bf(a4[1][j]);
        av1[j] = f2bf(a4[2][j]); av1[4 + j] = f2bf(a4[3][j]);
      }
      *(u16x8*)(&As[arow][aseg * 8])      = av0;
      *(u16x8*)(&As[arow + 64][aseg * 8]) = av1;
      if constexpr (M1 == 1){
        if (dog){
          *(u16x8*)(x0b + (size_t)(bm0 + arow) * Dd + k0 + aseg * 8)      = av0;
          *(u16x8*)(x0b + (size_t)(bm0 + arow + 64) * Dd + k0 + aseg * 8) = av1;
        }
      }
    } else {
      *(u16x8*)(&As[arow][aseg * 8])      = ar0;
      *(u16x8*)(&As[arow + 64][aseg * 8]) = ar1;
    }
    *(u16x8*)(&Bs[arow][aseg * 8])      = br0;
    *(u16x8*)(&Bs[arow + 64][aseg * 8]) = br1;
    __syncthreads();

    // fused gate partials (uses this step's a4 before prefetch clobbers it)
    if constexpr (M1 == 1){
      if (dog){
        u16x8 g0v = *(const u16x8*)(gw16 + (size_t)0 * Dd + k0 + aseg * 8);
        u16x8 g1v = *(const u16x8*)(gw16 + (size_t)1 * Dd + k0 + aseg * 8);
        u16x8 g2v = *(const u16x8*)(gw16 + (size_t)2 * Dd + k0 + aseg * 8);
        u16x8 g3v = *(const u16x8*)(gw16 + (size_t)3 * Dd + k0 + aseg * 8);
        #pragma unroll
        for (int u = 0; u < 8; u++){
          float xa = (u < 4) ? a4[0][u] : a4[1][u - 4];
          float xc = (u < 4) ? a4[2][u] : a4[3][u - 4];
          float g0 = bf2f(g0v[u]), g1 = bf2f(g1v[u]), g2 = bf2f(g2v[u]), g3 = bf2f(g3v[u]);
          sg0[0] += xa * g0; sg0[1] += xa * g1; sg0[2] += xa * g2; sg0[3] += xa * g3;
          sg1[0] += xc * g0; sg1[1] += xc * g1; sg1[2] += xc * g2; sg1[3] += xc * g3;
        }
      }
    }

    int kn = k0 + 32;
    if (kn < kc0 + 512){
      if constexpr (M1 != 0){
        a4[0] = *(const f32x4*)(Af + (size_t)(bm0 + arow) * Dd + kn + aseg * 8);
        a4[1] = *(const f32x4*)(Af + (size_t)(bm0 + arow) * Dd + kn + aseg * 8 + 4);
        a4[2] = *(const f32x4*)(Af + (size_t)(bm0 + arow + 64) * Dd + kn + aseg * 8);
        a4[3] = *(const f32x4*)(Af + (size_t)(bm0 + arow + 64) * Dd + kn + aseg * 8 + 4);
      } else {
        ar0 = *(const u16x8*)(Ab + (size_t)(bm0 + arow) * Dd + kn + aseg * 8);
        ar1 = *(const u16x8*)(Ab + (size_t)(bm0 + arow + 64) * Dd + kn + aseg * 8);
      }
      br0 = *(const u16x8*)(BT + (size_t)(bn0 + arow) * Dd + kn + aseg * 8);
      br1 = *(const u16x8*)(BT + (size_t)(bn0 + arow + 64) * Dd + kn + aseg * 8);
    }

    bf16x8 af[4];
    #pragma unroll
    for (int mi = 0; mi < 4; mi++)
      af[mi] = *reinterpret_cast<const bf16x8*>(&As[wm * 64 + mi * 16 + (lane & 15)][(lane >> 4) * 8]);
    #pragma unroll
    for (int nj = 0; nj < 4; nj++){
      bf16x8 bfr = *reinterpret_cast<const bf16x8*>(&Bs[wn * 64 + nj * 16 + (lane & 15)][(lane >> 4) * 8]);
      #pragma unroll
      for (int mi = 0; mi < 4; mi++)
        acc[mi][nj] = __builtin_amdgcn_mfma_f32_16x16x32_bf16(af[mi], bfr, acc[mi][nj], 0, 0, 0);
    }
  }

  // gate partial reduce across the 4 aseg lanes, write plog[z]
  if constexpr (M1 == 1){
    if (dog){
      #pragma unroll
      for (int e = 0; e < 4; e++){
        sg0[e] += __shfl_xor(sg0[e], 1, 64); sg0[e] += __shfl_xor(sg0[e], 2, 64);
        sg1[e] += __shfl_xor(sg1[e], 1, 64); sg1[e] += __shfl_xor(sg1[e], 2, 64);
      }
      if (aseg == 0){
        f32x4 p0; p0[0] = sg0[0]; p0[1] = sg0[1]; p0[2] = sg0[2]; p0[3] = sg0[3];
        f32x4 p1; p1[0] = sg1[0]; p1[1] = sg1[1]; p1[2] = sg1[2]; p1[3] = sg1[3];
        *(f32x4*)(plog + ((size_t)z * Bb + bm0 + arow) * 4) = p0;
        *(f32x4*)(plog + ((size_t)z * Bb + bm0 + arow + 64) * 4) = p1;
      }
    }
  }

  // epilogue: 4 quarter-phases of 32 rows -> bf16 partials (z-plane)
  unsigned short* outz = vxp + (size_t)z * Bb * 256;
  #pragma unroll
  for (int h = 0; h < 4; h++){
    __syncthreads();
    if (wm == (h >> 1)){
      const int mib = (h & 1) * 2;
      #pragma unroll
      for (int m2 = 0; m2 < 2; m2++)
        #pragma unroll
        for (int nj = 0; nj < 4; nj++)
          #pragma unroll
          for (int q = 0; q < 4; q++)
            epi[m2 * 16 + (lane >> 4) * 4 + q][wn * 64 + nj * 16 + (lane & 15)] = acc[mib + m2][nj][q];
    }
    __syncthreads();
    #pragma unroll
    for (int c = 0; c < 2; c++){
      int idx = c * 256 + tid;
      int r = idx >> 4;
      int col = (idx & 15) * 8;
      f32x4 v0 = *(const f32x4*)&epi[r][col];
      f32x4 v1 = *(const f32x4*)&epi[r][col + 4];
      u16x8 ov;
      #pragma unroll
      for (int j = 0; j < 4; j++){ ov[j] = f2bf(v0[j]); ov[4 + j] = f2bf(v1[j]); }
      *(u16x8*)(outz + (size_t)(bm0 + h * 32 + r) * 256 + bn0 + col) = ov;
    }
  }
}

// ============ G2: block-diag C; sums bf16 partials ============
// NPART==0: gate weights from gsb. NPART==4: sum 4 plog partials (from gemm1 l=0).
// NPART==16: sum 16 plog partials (from gemm3 fused gate, l>=1).
template<int NPART>
__global__ __launch_bounds__(256) void gemm2_k(const unsigned short* __restrict__ vxp,
                                               const unsigned short* __restrict__ cb,
                                               const float* __restrict__ gsb,
                                               const float* __restrict__ plog,
                                               unsigned short* __restrict__ wb){
  const int bm0 = blockIdx.x * 64;
  const int e   = blockIdx.y;
  const int tid = threadIdx.x;
  const int lane = tid & 63;
  const int wv = tid >> 6;
  const int wm = wv >> 1, wn = wv & 1;

  __shared__ __align__(16) char smraw[19456];
  unsigned short (*As)[72] = (unsigned short (*)[72])smraw;            // 9216
  unsigned short (*Bs)[72] = (unsigned short (*)[72])(smraw + 9216);   // 9216
  float (*gs_l)[4] = (float (*)[4])(smraw + 18432);                    // 1024
  unsigned short (*epi)[72] = (unsigned short (*)[72])smraw;           // union As

  if constexpr (NPART > 0){
    int r = tid >> 2, q = tid & 3;
    f32x4 s = {0.f, 0.f, 0.f, 0.f};
    #pragma unroll
    for (int ci = 0; ci < NPART / 4; ci++)
      s += *(const f32x4*)(plog + ((size_t)(q * (NPART / 4) + ci) * Bb + bm0 + r) * 4);
    #pragma unroll
    for (int j = 0; j < 4; j++){
      s[j] += __shfl_xor(s[j], 1, 64);
      s[j] += __shfl_xor(s[j], 2, 64);
    }
    if (q == 0){
      float mx = fmaxf(fmaxf(s[0], s[1]), fmaxf(s[2], s[3]));
      float e0 = __expf(s[0] - mx), e1 = __expf(s[1] - mx), e2 = __expf(s[2] - mx), e3 = __expf(s[3] - mx);
      float inv = 1.f / (e0 + e1 + e2 + e3);
      f32x4 g; g[0] = e0 * inv; g[1] = e1 * inv; g[2] = e2 * inv; g[3] = e3 * inv;
      *(f32x4*)&gs_l[r][0] = g;
    }
  } else {
    if (tid < 64) *(f32x4*)&gs_l[tid][0] = *(const f32x4*)(gsb + (size_t)(bm0 + tid) * 4);
  }

  const int arow = tid >> 2;
  const int aseg = tid & 3;

  float tv[16];
  #pragma unroll
  for (int j = 0; j < 16; j++) tv[j] = 0.f;
  #pragma unroll
  for (int z = 0; z < 4; z++){
    const unsigned short* vz = vxp + ((size_t)z * Bb + bm0 + arow) * 256 + e * 64 + aseg * 16;
    u16x8 p0 = *(const u16x8*)vz;
    u16x8 p1 = *(const u16x8*)(vz + 8);
    #pragma unroll
    for (int j = 0; j < 8; j++){ tv[j] += bf2f(p0[j]); tv[8 + j] += bf2f(p1[j]); }
  }
  u16x8 av0, av1;
  #pragma unroll
  for (int j = 0; j < 4; j++){
    av0[j] = f2bf(tanhf(tv[j]));     av0[4 + j] = f2bf(tanhf(tv[4 + j]));
    av1[j] = f2bf(tanhf(tv[8 + j])); av1[4 + j] = f2bf(tanhf(tv[12 + j]));
  }
  *(u16x8*)(&As[arow][aseg * 16]) = av0;
  *(u16x8*)(&As[arow][aseg * 16 + 8]) = av1;
  *(u16x8*)(&Bs[arow][aseg * 16])     = *(const u16x8*)(cb + e * 4096 + arow * 64 + aseg * 16);
  *(u16x8*)(&Bs[arow][aseg * 16 + 8]) = *(const u16x8*)(cb + e * 4096 + arow * 64 + aseg * 16 + 8);
  __syncthreads();

  f32x4 acc[2][2] = {};
  #pragma unroll
  for (int kk = 0; kk < 2; kk++){
    bf16x8 af[2];
    #pragma unroll
    for (int mi = 0; mi < 2; mi++)
      af[mi] = *reinterpret_cast<const bf16x8*>(&As[wm * 32 + mi * 16 + (lane & 15)][kk * 32 + (lane >> 4) * 8]);
    #pragma unroll
    for (int nj = 0; nj < 2; nj++){
      bf16x8 bfr = *reinterpret_cast<const bf16x8*>(&Bs[wn * 32 + nj * 16 + (lane & 15)][kk * 32 + (lane >> 4) * 8]);
      #pragma unroll
      for (int mi = 0; mi < 2; mi++)
        acc[mi][nj] = __builtin_amdgcn_mfma_f32_16x16x32_bf16(af[mi], bfr, acc[mi][nj], 0, 0, 0);
    }
  }

  __syncthreads();
  #pragma unroll
  for (int mi = 0; mi < 2; mi++)
    #pragma unroll
    for (int nj = 0; nj < 2; nj++)
      #pragma unroll
      for (int q = 0; q < 4; q++){
        int row = wm * 32 + mi * 16 + (lane >> 4) * 4 + q;
        int col = wn * 32 + nj * 16 + (lane & 15);
        float g = gs_l[row][e];
        epi[row][col] = f2bf(g * tanhf(acc[mi][nj][q]));
      }
  __syncthreads();
  #pragma unroll
  for (int c = 0; c < 2; c++){
    int idx = c * 256 + tid;
    int row = idx >> 3;
    int col = (idx & 7) * 8;
    *(u16x8*)(wb + (size_t)(bm0 + row) * 256 + e * 64 + col) = *(const u16x8*)(&epi[row][col]);
  }
}

// ============ G3: Y = wb @ UfT; x_new = xold + x0*(bias + Y); fused next-gate ============
// 128x128 tile, 4 waves each 64x64, BK=32, inline epilogue (round-7 proven, 38us).
template<int MODE, bool X0BF>
__global__ __launch_bounds__(256, 4) void gemm3_k(const unsigned short* __restrict__ A,
                                                  const unsigned short* __restrict__ BT,
                                                  const float* __restrict__ x0f,
                                                  const unsigned short* __restrict__ x0b,
                                                  unsigned short* __restrict__ xst,
                                                  const float* __restrict__ biasrow,
                                                  float* __restrict__ out,
                                                  const unsigned short* __restrict__ gw16,
                                                  float* __restrict__ plog){
  const int bm0 = blockIdx.x * 128;
  const int bn0 = blockIdx.y * 128;
  const int tid = threadIdx.x;
  const int lane = tid & 63;
  const int wv = tid >> 6;
  const int wm = wv >> 1, wn = wv & 1;

  __shared__ __align__(16) char smraw[20480];
  unsigned short (*As)[40] = (unsigned short (*)[40])smraw;            // 10240 B
  unsigned short (*Bs)[40] = (unsigned short (*)[40])(smraw + 10240);  // 10240 B
  float (*epi)[132] = (float (*)[132])smraw;                           // 16896 B

  f32x4 acc[4][4] = {};
  const int arow = tid >> 2;
  const int aseg = tid & 3;

  u16x8 ar0 = *(const u16x8*)(A + (size_t)(bm0 + arow) * 256 + aseg * 8);
  u16x8 ar1 = *(const u16x8*)(A + (size_t)(bm0 + arow + 64) * 256 + aseg * 8);
  u16x8 br0 = *(const u16x8*)(BT + (size_t)(bn0 + arow) * 256 + aseg * 8);
  u16x8 br1 = *(const u16x8*)(BT + (size_t)(bn0 + arow + 64) * 256 + aseg * 8);

  for (int k0 = 0; k0 < 256; k0 += 32){
    __syncthreads();
    *(u16x8*)(&As[arow][aseg * 8])      = ar0;
    *(u16x8*)(&As[arow + 64][aseg * 8]) = ar1;
    *(u16x8*)(&Bs[arow][aseg * 8])      = br0;
    *(u16x8*)(&Bs[arow + 64][aseg * 8]) = br1;
    __syncthreads();
    if (k0 + 32 < 256){
      ar0 = *(const u16x8*)(A + (size_t)(bm0 + arow) * 256 + k0 + 32 + aseg * 8);
      ar1 = *(const u16x8*)(A + (size_t)(bm0 + arow + 64) * 256 + k0 + 32 + aseg * 8);
      br0 = *(const u16x8*)(BT + (size_t)(bn0 + arow) * 256 + k0 + 32 + aseg * 8);
      br1 = *(const u16x8*)(BT + (size_t)(bn0 + arow + 64) * 256 + k0 + 32 + aseg * 8);
    }
    bf16x8 af[4];
    #pragma unroll
    for (int mi = 0; mi < 4; mi++)
      af[mi] = *reinterpret_cast<const bf16x8*>(&As[wm * 64 + mi * 16 + (lane & 15)][(lane >> 4) * 8]);
    #pragma unroll
    for (int nj = 0; nj < 4; nj++){
      bf16x8 bfr = *reinterpret_cast<const bf16x8*>(&Bs[wn * 64 + nj * 16 + (lane & 15)][(lane >> 4) * 8]);
      #pragma unroll
      for (int mi = 0; mi < 4; mi++)
        acc[mi][nj] = __builtin_amdgcn_mfma_f32_16x16x32_bf16(af[mi], bfr, acc[mi][nj], 0, 0, 0);
    }
  }

  // epilogue: 4 quarter-phases of 32 rows each through LDS, inline operand loads
  #pragma unroll
  for (int h = 0; h < 4; h++){
    __syncthreads();
    if (wm == (h >> 1)){
      const int mib = (h & 1) * 2;
      #pragma unroll
      for (int m2 = 0; m2 < 2; m2++)
        #pragma unroll
        for (int nj = 0; nj < 4; nj++)
          #pragma unroll
          for (int q = 0; q < 4; q++)
            epi[m2 * 16 + (lane >> 4) * 4 + q][wn * 64 + nj * 16 + (lane & 15)] = acc[mib + m2][nj][q];
    }
    __syncthreads();
    #pragma unroll
    for (int c = 0; c < 4; c++){
      int idx = c * 256 + tid;
      int r = idx >> 5;
      int col = (idx & 31) * 4;
      int row = bm0 + h * 32 + r;
      size_t o = (size_t)row * Dd + bn0 + col;
      f32x4 y = *(const f32x4*)&epi[r][col];
      f32x4 bv = *(const f32x4*)(biasrow + bn0 + col);
      f32x4 x0v;
      if constexpr (X0BF){
        u16x4 xv = *(const u16x4*)(x0b + o);
        #pragma unroll
        for (int j = 0; j < 4; j++) x0v[j] = bf2f(xv[j]);
      } else {
        x0v = *(const f32x4*)(x0f + o);
      }
      f32x4 xo;
      if constexpr (MODE == 0){
        xo = x0v;
      } else {
        u16x4 xv = *(const u16x4*)(xst + o);
        #pragma unroll
        for (int j = 0; j < 4; j++) xo[j] = bf2f(xv[j]);
      }
      f32x4 xn;
      #pragma unroll
      for (int j = 0; j < 4; j++) xn[j] = xo[j] + x0v[j] * (bv[j] + y[j]);
      if constexpr (MODE == 2){
        *(f32x4*)(out + o) = xn;
      } else {
        u16x4 xnb;
        #pragma unroll
        for (int j = 0; j < 4; j++) xnb[j] = f2bf(xn[j]);
        *(u16x4*)(xst + o) = xnb;
      }
      if constexpr (MODE != 2){
        float s[4];
        #pragma unroll
        for (int e = 0; e < 4; e++){
          u16x4 gv = *(const u16x4*)(gw16 + (size_t)e * Dd + bn0 + col);
          s[e] = xn[0] * bf2f(gv[0]) + xn[1] * bf2f(gv[1])
               + xn[2] * bf2f(gv[2]) + xn[3] * bf2f(gv[3]);
        }
        #pragma unroll
        for (int m = 1; m < 32; m <<= 1)
          #pragma unroll
          for (int e = 0; e < 4; e++) s[e] += __shfl_xor(s[e], m, 64);
        if ((tid & 31) == 0){
          f32x4 pv; pv[0] = s[0]; pv[1] = s[1]; pv[2] = s[2]; pv[3] = s[3];
          *(f32x4*)(plog + ((size_t)blockIdx.y * Bb + row) * 4) = pv;
        }
      }
    }
  }
}

extern "C" void kernel_launch(void* const* d_in, const int* in_sizes, int n_in,
                              void* d_out, int out_size, void* d_ws, size_t ws_size,
                              hipStream_t stream){
  (void)in_sizes; (void)n_in; (void)out_size;
  const float* inp  = (const float*)d_in[0];
  const float* U    = (const float*)d_in[1];
  const float* V    = (const float*)d_in[2];
  const float* C    = (const float*)d_in[3];
  const float* gw   = (const float*)d_in[4];
  const float* bias = (const float*)d_in[5];
  float* out = (float*)d_out;

  char* ws = (char*)d_ws;
  size_t o = 0;
  unsigned short* xb  = (unsigned short*)(ws + o); o += (size_t)Bb * Dd * 2;          // 33.55 MB (bf16 state)
  unsigned short* vxp = (unsigned short*)(ws + o); o += (size_t)4 * Bb * 256 * 2;     // 16.78 MB (bf16 partials)
  unsigned short* wb  = (unsigned short*)(ws + o); o += (size_t)Bb * 256 * 2;         //  4.19 MB
  float*          gsb = (float*)(ws + o);          o += (size_t)Bb * 4 * 4;           //  0.13 MB
  float*          plog= (float*)(ws + o);          o += (size_t)16 * Bb * 4 * 4;      //  2.10 MB
  unsigned short* vft = (unsigned short*)(ws + o); o += (size_t)Ll * 256 * Dd * 2;    //  3.15 MB
  unsigned short* uft = (unsigned short*)(ws + o); o += (size_t)Ll * Dd * 256 * 2;    //  3.15 MB
  unsigned short* cb16= (unsigned short*)(ws + o); o += (size_t)Ll * Ee * Rr * Rr * 2;//  0.10 MB
  unsigned short* g16 = (unsigned short*)(ws + o); o += (size_t)Ee * Dd * 2;          //  0.02 MB
  if (ws_size < o) return;
  unsigned short* x0b = nullptr;
  if (ws_size >= o + (size_t)Bb * Dd * 2){
    x0b = (unsigned short*)(ws + o); o += (size_t)Bb * Dd * 2;                        // 33.55 MB (bf16 x0)
  }
  const bool hx = (x0b != nullptr);

  prep_w_k<<<1024, 256, 0, stream>>>(U, V, C, gw, vft, uft, cb16, g16);

  for (int l = 0; l < Ll; l++){
    const unsigned short* vftl = vft + (size_t)l * 256 * Dd;
    const unsigned short* uftl = uft + (size_t)l * Dd * 256;
    const unsigned short* cbl  = cb16 + (size_t)l * Ee * Rr * Rr;
    const float* biasl = bias + (size_t)l * Dd;

    if (l == 0){
      if (hx){
        // fused: gemm1 reads fp32 inp, writes bf16 x0b + 4 gate-logit partials
        gemm1_k<1><<<dim3(Bb / 128, 2, 4), 256, 0, stream>>>(inp, vftl, vxp, x0b, g16, plog);
        gemm2_k<4><<<dim3(Bb / 64, Ee), 256, 0, stream>>>(vxp, cbl, gsb, plog, wb);
      } else {
        gate_k<<<Bb / 4, 256, 0, stream>>>(inp, g16, gsb);
        gemm1_k<2><<<dim3(Bb / 128, 2, 4), 256, 0, stream>>>(inp, vftl, vxp, nullptr, g16, plog);
        gemm2_k<0><<<dim3(Bb / 64, Ee), 256, 0, stream>>>(vxp, cbl, gsb, plog, wb);
      }
    } else {
      gemm1_k<0><<<dim3(Bb / 128, 2, 4), 256, 0, stream>>>(xb, vftl, vxp, nullptr, g16, plog);
      gemm2_k<16><<<dim3(Bb / 64, Ee), 256, 0, stream>>>(vxp, cbl, gsb, plog, wb);
    }

    dim3 g3(Bb / 128, Dd / 128);
    if (l == 0){
      if (hx) gemm3_k<0, true ><<<g3, 256, 0, stream>>>(wb, uftl, inp, x0b, xb, biasl, out, g16, plog);
      else    gemm3_k<0, false><<<g3, 256, 0, stream>>>(wb, uftl, inp, x0b, xb, biasl, out, g16, plog);
    } else if (l == 1){
      if (hx) gemm3_k<1, true ><<<g3, 256, 0, stream>>>(wb, uftl, inp, x0b, xb, biasl, out, g16, plog);
      else    gemm3_k<1, false><<<g3, 256, 0, stream>>>(wb, uftl, inp, x0b, xb, biasl, out, g16, plog);
    } else {
      if (hx) gemm3_k<2, true ><<<g3, 256, 0, stream>>>(wb, uftl, inp, x0b, xb, biasl, out, g16, plog);
      else    gemm3_k<2, false><<<g3, 256, 0, stream>>>(wb, uftl, inp, x0b, xb, biasl, out, g16, plog);
    }
  }
}

// Round 14
// 206.761 us; speedup vs baseline: 1.1034x; 1.0088x over previous
//
#include <hip/hip_runtime.h>
#include <cmath>

#define Bb 8192
#define Dd 2048
#define Rr 64
#define Ee 4
#define Ll 3

typedef __bf16 bf16x8 __attribute__((ext_vector_type(8)));
typedef float f32x4 __attribute__((ext_vector_type(4)));
typedef unsigned short u16x8 __attribute__((ext_vector_type(8)));
typedef unsigned short u16x4 __attribute__((ext_vector_type(4)));

__device__ __forceinline__ unsigned short f2bf(float f){
  unsigned u = __builtin_bit_cast(unsigned, f);
  u += 0x7fffu + ((u >> 16) & 1u);
  return (unsigned short)(u >> 16);
}
__device__ __forceinline__ float bf2f(unsigned short h){
  return __builtin_bit_cast(float, ((unsigned)h) << 16);
}

// ---------------- prep: transpose/cast weights ----------------
__global__ __launch_bounds__(256) void prep_w_k(const float* __restrict__ U,
                                                const float* __restrict__ V,
                                                const float* __restrict__ C,
                                                const float* __restrict__ gw,
                                                unsigned short* __restrict__ VfT,
                                                unsigned short* __restrict__ UfT,
                                                unsigned short* __restrict__ cb16,
                                                unsigned short* __restrict__ gw16){
  const int NV = Ll * 256 * Dd;
  const int NU = Ll * Dd * 256;
  const int NC = Ll * Ee * Rr * Rr;
  const int NG = Ee * Dd;
  const int total = NV + NU + NC + NG;
  for (int idx = blockIdx.x * blockDim.x + threadIdx.x; idx < total; idx += gridDim.x * blockDim.x){
    if (idx < NV){
      int l = idx / (256 * Dd); int rem = idx - l * 256 * Dd;
      int n = rem / Dd, d = rem - n * Dd;
      int e = n >> 6, r = n & 63;
      VfT[idx] = f2bf(V[(((size_t)l * Ee + e) * Dd + d) * Rr + r]);
    } else if (idx < NV + NU){
      int j = idx - NV;
      int l = j / (Dd * 256); int rem = j - l * Dd * 256;
      int d = rem / 256, k = rem - d * 256;
      int e = k >> 6, s = k & 63;
      UfT[j] = f2bf(U[(((size_t)l * Ee + e) * Dd + d) * Rr + s]);
    } else if (idx < NV + NU + NC){
      int j = idx - NV - NU;
      cb16[j] = f2bf(C[j]);
    } else {
      int j = idx - NV - NU - NC;
      gw16[j] = f2bf(gw[j]);
    }
  }
}

// ---------------- gate (fallback, fp32 input): one wave per row ----------------
__global__ __launch_bounds__(256) void gate_k(const float* __restrict__ xv,
                                              const unsigned short* __restrict__ gw16,
                                              float* __restrict__ gs){
  const int lane = threadIdx.x & 63;
  const int w = threadIdx.x >> 6;
  const int row = blockIdx.x * 4 + w;
  float s0 = 0.f, s1 = 0.f, s2 = 0.f, s3 = 0.f;
  #pragma unroll
  for (int c = 0; c < 4; c++){
    const int k = c * 512 + lane * 8;
    const float* xr = xv + (size_t)row * Dd + k;
    f32x4 v0 = *(const f32x4*)xr;
    f32x4 v1 = *(const f32x4*)(xr + 4);
    float xf[8];
    #pragma unroll
    for (int u = 0; u < 4; u++){ xf[u] = v0[u]; xf[4 + u] = v1[u]; }
    u16x8 g0v = *(const u16x8*)(gw16 + 0 * Dd + k);
    u16x8 g1v = *(const u16x8*)(gw16 + 1 * Dd + k);
    u16x8 g2v = *(const u16x8*)(gw16 + 2 * Dd + k);
    u16x8 g3v = *(const u16x8*)(gw16 + 3 * Dd + k);
    #pragma unroll
    for (int u = 0; u < 8; u++){
      s0 += xf[u] * bf2f(g0v[u]);
      s1 += xf[u] * bf2f(g1v[u]);
      s2 += xf[u] * bf2f(g2v[u]);
      s3 += xf[u] * bf2f(g3v[u]);
    }
  }
  #pragma unroll
  for (int m = 1; m < 64; m <<= 1){
    s0 += __shfl_xor(s0, m, 64);
    s1 += __shfl_xor(s1, m, 64);
    s2 += __shfl_xor(s2, m, 64);
    s3 += __shfl_xor(s3, m, 64);
  }
  if (lane == 0){
    float mx = fmaxf(fmaxf(s0, s1), fmaxf(s2, s3));
    float e0 = __expf(s0 - mx), e1 = __expf(s1 - mx), e2 = __expf(s2 - mx), e3 = __expf(s3 - mx);
    float inv = 1.f / (e0 + e1 + e2 + e3);
    f32x4 g; g[0] = e0 * inv; g[1] = e1 * inv; g[2] = e2 * inv; g[3] = e3 * inv;
    *(f32x4*)(gs + (size_t)row * 4) = g;
  }
}

// ============ G1: T = X @ VfT, split-K=4, bf16 partials ============
// 128x128 tile, 4 waves each 64x64, BK=32, reg-prefetch. grid (Bb/128, 2, 4).
// M1==0: A is bf16. M1==1: A fp32 inp, bn==0 blocks write x0b + plog. M1==2: fp32 plain.
template<int M1>
__global__ __launch_bounds__(256) void gemm1_k(const void* __restrict__ Av,
                                               const unsigned short* __restrict__ BT,
                                               unsigned short* __restrict__ vxp,
                                               unsigned short* __restrict__ x0b,
                                               const unsigned short* __restrict__ gw16,
                                               float* __restrict__ plog){
  const int bm0 = blockIdx.x * 128;
  const int bn0 = blockIdx.y * 128;
  const int z   = blockIdx.z;
  const int kc0 = z * 512;
  const int tid = threadIdx.x;
  const int lane = tid & 63;
  const int wv = tid >> 6;
  const int wm = wv >> 1, wn = wv & 1;

  __shared__ __align__(16) char smraw[20480];
  unsigned short (*As)[40] = (unsigned short (*)[40])smraw;            // 10240 B
  unsigned short (*Bs)[40] = (unsigned short (*)[40])(smraw + 10240);  // 10240 B
  float (*epi)[132] = (float (*)[132])smraw;                           // 16896 B (union)

  f32x4 acc[4][4] = {};
  const int arow = tid >> 2;
  const int aseg = tid & 3;

  const float* Af = (const float*)Av;
  const unsigned short* Ab = (const unsigned short*)Av;
  const bool dog = (M1 == 1) && (bn0 == 0);

  float sg0[4] = {0.f, 0.f, 0.f, 0.f};
  float sg1[4] = {0.f, 0.f, 0.f, 0.f};

  f32x4 a4[4]; u16x8 ar0, ar1;
  u16x8 br0, br1;
  if constexpr (M1 != 0){
    a4[0] = *(const f32x4*)(Af + (size_t)(bm0 + arow) * Dd + kc0 + aseg * 8);
    a4[1] = *(const f32x4*)(Af + (size_t)(bm0 + arow) * Dd + kc0 + aseg * 8 + 4);
    a4[2] = *(const f32x4*)(Af + (size_t)(bm0 + arow + 64) * Dd + kc0 + aseg * 8);
    a4[3] = *(const f32x4*)(Af + (size_t)(bm0 + arow + 64) * Dd + kc0 + aseg * 8 + 4);
  } else {
    ar0 = *(const u16x8*)(Ab + (size_t)(bm0 + arow) * Dd + kc0 + aseg * 8);
    ar1 = *(const u16x8*)(Ab + (size_t)(bm0 + arow + 64) * Dd + kc0 + aseg * 8);
  }
  br0 = *(const u16x8*)(BT + (size_t)(bn0 + arow) * Dd + kc0 + aseg * 8);
  br1 = *(const u16x8*)(BT + (size_t)(bn0 + arow + 64) * Dd + kc0 + aseg * 8);

  for (int k0 = kc0; k0 < kc0 + 512; k0 += 32){
    __syncthreads();
    if constexpr (M1 != 0){
      u16x8 av0, av1;
      #pragma unroll
      for (int j = 0; j < 4; j++){
        av0[j] = f2bf(a4[0][j]); av0[4 + j] = f2bf(a4[1][j]);
        av1[j] = f2bf(a4[2][j]); av1[4 + j] = f2bf(a4[3][j]);
      }
      *(u16x8*)(&As[arow][aseg * 8])      = av0;
      *(u16x8*)(&As[arow + 64][aseg * 8]) = av1;
      if constexpr (M1 == 1){
        if (dog){
          *(u16x8*)(x0b + (size_t)(bm0 + arow) * Dd + k0 + aseg * 8)      = av0;
          *(u16x8*)(x0b + (size_t)(bm0 + arow + 64) * Dd + k0 + aseg * 8) = av1;
        }
      }
    } else {
      *(u16x8*)(&As[arow][aseg * 8])      = ar0;
      *(u16x8*)(&As[arow + 64][aseg * 8]) = ar1;
    }
    *(u16x8*)(&Bs[arow][aseg * 8])      = br0;
    *(u16x8*)(&Bs[arow + 64][aseg * 8]) = br1;
    __syncthreads();

    if constexpr (M1 == 1){
      if (dog){
        u16x8 g0v = *(const u16x8*)(gw16 + (size_t)0 * Dd + k0 + aseg * 8);
        u16x8 g1v = *(const u16x8*)(gw16 + (size_t)1 * Dd + k0 + aseg * 8);
        u16x8 g2v = *(const u16x8*)(gw16 + (size_t)2 * Dd + k0 + aseg * 8);
        u16x8 g3v = *(const u16x8*)(gw16 + (size_t)3 * Dd + k0 + aseg * 8);
        #pragma unroll
        for (int u = 0; u < 8; u++){
          float xa = (u < 4) ? a4[0][u] : a4[1][u - 4];
          float xc = (u < 4) ? a4[2][u] : a4[3][u - 4];
          float g0 = bf2f(g0v[u]), g1 = bf2f(g1v[u]), g2 = bf2f(g2v[u]), g3 = bf2f(g3v[u]);
          sg0[0] += xa * g0; sg0[1] += xa * g1; sg0[2] += xa * g2; sg0[3] += xa * g3;
          sg1[0] += xc * g0; sg1[1] += xc * g1; sg1[2] += xc * g2; sg1[3] += xc * g3;
        }
      }
    }

    int kn = k0 + 32;
    if (kn < kc0 + 512){
      if constexpr (M1 != 0){
        a4[0] = *(const f32x4*)(Af + (size_t)(bm0 + arow) * Dd + kn + aseg * 8);
        a4[1] = *(const f32x4*)(Af + (size_t)(bm0 + arow) * Dd + kn + aseg * 8 + 4);
        a4[2] = *(const f32x4*)(Af + (size_t)(bm0 + arow + 64) * Dd + kn + aseg * 8);
        a4[3] = *(const f32x4*)(Af + (size_t)(bm0 + arow + 64) * Dd + kn + aseg * 8 + 4);
      } else {
        ar0 = *(const u16x8*)(Ab + (size_t)(bm0 + arow) * Dd + kn + aseg * 8);
        ar1 = *(const u16x8*)(Ab + (size_t)(bm0 + arow + 64) * Dd + kn + aseg * 8);
      }
      br0 = *(const u16x8*)(BT + (size_t)(bn0 + arow) * Dd + kn + aseg * 8);
      br1 = *(const u16x8*)(BT + (size_t)(bn0 + arow + 64) * Dd + kn + aseg * 8);
    }

    bf16x8 af[4];
    #pragma unroll
    for (int mi = 0; mi < 4; mi++)
      af[mi] = *reinterpret_cast<const bf16x8*>(&As[wm * 64 + mi * 16 + (lane & 15)][(lane >> 4) * 8]);
    #pragma unroll
    for (int nj = 0; nj < 4; nj++){
      bf16x8 bfr = *reinterpret_cast<const bf16x8*>(&Bs[wn * 64 + nj * 16 + (lane & 15)][(lane >> 4) * 8]);
      #pragma unroll
      for (int mi = 0; mi < 4; mi++)
        acc[mi][nj] = __builtin_amdgcn_mfma_f32_16x16x32_bf16(af[mi], bfr, acc[mi][nj], 0, 0, 0);
    }
  }

  if constexpr (M1 == 1){
    if (dog){
      #pragma unroll
      for (int e = 0; e < 4; e++){
        sg0[e] += __shfl_xor(sg0[e], 1, 64); sg0[e] += __shfl_xor(sg0[e], 2, 64);
        sg1[e] += __shfl_xor(sg1[e], 1, 64); sg1[e] += __shfl_xor(sg1[e], 2, 64);
      }
      if (aseg == 0){
        f32x4 p0; p0[0] = sg0[0]; p0[1] = sg0[1]; p0[2] = sg0[2]; p0[3] = sg0[3];
        f32x4 p1; p1[0] = sg1[0]; p1[1] = sg1[1]; p1[2] = sg1[2]; p1[3] = sg1[3];
        *(f32x4*)(plog + ((size_t)z * Bb + bm0 + arow) * 4) = p0;
        *(f32x4*)(plog + ((size_t)z * Bb + bm0 + arow + 64) * 4) = p1;
      }
    }
  }

  unsigned short* outz = vxp + (size_t)z * Bb * 256;
  #pragma unroll
  for (int h = 0; h < 4; h++){
    __syncthreads();
    if (wm == (h >> 1)){
      const int mib = (h & 1) * 2;
      #pragma unroll
      for (int m2 = 0; m2 < 2; m2++)
        #pragma unroll
        for (int nj = 0; nj < 4; nj++)
          #pragma unroll
          for (int q = 0; q < 4; q++)
            epi[m2 * 16 + (lane >> 4) * 4 + q][wn * 64 + nj * 16 + (lane & 15)] = acc[mib + m2][nj][q];
    }
    __syncthreads();
    #pragma unroll
    for (int c = 0; c < 2; c++){
      int idx = c * 256 + tid;
      int r = idx >> 4;
      int col = (idx & 15) * 8;
      f32x4 v0 = *(const f32x4*)&epi[r][col];
      f32x4 v1 = *(const f32x4*)&epi[r][col + 4];
      u16x8 ov;
      #pragma unroll
      for (int j = 0; j < 4; j++){ ov[j] = f2bf(v0[j]); ov[4 + j] = f2bf(v1[j]); }
      *(u16x8*)(outz + (size_t)(bm0 + h * 32 + r) * 256 + bn0 + col) = ov;
    }
  }
}

// ============ G2: block-diag C; sums bf16 partials ============
template<int NPART>
__global__ __launch_bounds__(256) void gemm2_k(const unsigned short* __restrict__ vxp,
                                               const unsigned short* __restrict__ cb,
                                               const float* __restrict__ gsb,
                                               const float* __restrict__ plog,
                                               unsigned short* __restrict__ wb){
  const int bm0 = blockIdx.x * 64;
  const int e   = blockIdx.y;
  const int tid = threadIdx.x;
  const int lane = tid & 63;
  const int wv = tid >> 6;
  const int wm = wv >> 1, wn = wv & 1;

  __shared__ __align__(16) char smraw[19456];
  unsigned short (*As)[72] = (unsigned short (*)[72])smraw;
  unsigned short (*Bs)[72] = (unsigned short (*)[72])(smraw + 9216);
  float (*gs_l)[4] = (float (*)[4])(smraw + 18432);
  unsigned short (*epi)[72] = (unsigned short (*)[72])smraw;

  if constexpr (NPART > 0){
    int r = tid >> 2, q = tid & 3;
    f32x4 s = {0.f, 0.f, 0.f, 0.f};
    #pragma unroll
    for (int ci = 0; ci < NPART / 4; ci++)
      s += *(const f32x4*)(plog + ((size_t)(q * (NPART / 4) + ci) * Bb + bm0 + r) * 4);
    #pragma unroll
    for (int j = 0; j < 4; j++){
      s[j] += __shfl_xor(s[j], 1, 64);
      s[j] += __shfl_xor(s[j], 2, 64);
    }
    if (q == 0){
      float mx = fmaxf(fmaxf(s[0], s[1]), fmaxf(s[2], s[3]));
      float e0 = __expf(s[0] - mx), e1 = __expf(s[1] - mx), e2 = __expf(s[2] - mx), e3 = __expf(s[3] - mx);
      float inv = 1.f / (e0 + e1 + e2 + e3);
      f32x4 g; g[0] = e0 * inv; g[1] = e1 * inv; g[2] = e2 * inv; g[3] = e3 * inv;
      *(f32x4*)&gs_l[r][0] = g;
    }
  } else {
    if (tid < 64) *(f32x4*)&gs_l[tid][0] = *(const f32x4*)(gsb + (size_t)(bm0 + tid) * 4);
  }

  const int arow = tid >> 2;
  const int aseg = tid & 3;

  float tv[16];
  #pragma unroll
  for (int j = 0; j < 16; j++) tv[j] = 0.f;
  #pragma unroll
  for (int z = 0; z < 4; z++){
    const unsigned short* vz = vxp + ((size_t)z * Bb + bm0 + arow) * 256 + e * 64 + aseg * 16;
    u16x8 p0 = *(const u16x8*)vz;
    u16x8 p1 = *(const u16x8*)(vz + 8);
    #pragma unroll
    for (int j = 0; j < 8; j++){ tv[j] += bf2f(p0[j]); tv[8 + j] += bf2f(p1[j]); }
  }
  u16x8 av0, av1;
  #pragma unroll
  for (int j = 0; j < 4; j++){
    av0[j] = f2bf(tanhf(tv[j]));     av0[4 + j] = f2bf(tanhf(tv[4 + j]));
    av1[j] = f2bf(tanhf(tv[8 + j])); av1[4 + j] = f2bf(tanhf(tv[12 + j]));
  }
  *(u16x8*)(&As[arow][aseg * 16]) = av0;
  *(u16x8*)(&As[arow][aseg * 16 + 8]) = av1;
  *(u16x8*)(&Bs[arow][aseg * 16])     = *(const u16x8*)(cb + e * 4096 + arow * 64 + aseg * 16);
  *(u16x8*)(&Bs[arow][aseg * 16 + 8]) = *(const u16x8*)(cb + e * 4096 + arow * 64 + aseg * 16 + 8);
  __syncthreads();

  f32x4 acc[2][2] = {};
  #pragma unroll
  for (int kk = 0; kk < 2; kk++){
    bf16x8 af[2];
    #pragma unroll
    for (int mi = 0; mi < 2; mi++)
      af[mi] = *reinterpret_cast<const bf16x8*>(&As[wm * 32 + mi * 16 + (lane & 15)][kk * 32 + (lane >> 4) * 8]);
    #pragma unroll
    for (int nj = 0; nj < 2; nj++){
      bf16x8 bfr = *reinterpret_cast<const bf16x8*>(&Bs[wn * 32 + nj * 16 + (lane & 15)][kk * 32 + (lane >> 4) * 8]);
      #pragma unroll
      for (int mi = 0; mi < 2; mi++)
        acc[mi][nj] = __builtin_amdgcn_mfma_f32_16x16x32_bf16(af[mi], bfr, acc[mi][nj], 0, 0, 0);
    }
  }

  __syncthreads();
  #pragma unroll
  for (int mi = 0; mi < 2; mi++)
    #pragma unroll
    for (int nj = 0; nj < 2; nj++)
      #pragma unroll
      for (int q = 0; q < 4; q++){
        int row = wm * 32 + mi * 16 + (lane >> 4) * 4 + q;
        int col = wn * 32 + nj * 16 + (lane & 15);
        float g = gs_l[row][e];
        epi[row][col] = f2bf(g * tanhf(acc[mi][nj][q]));
      }
  __syncthreads();
  #pragma unroll
  for (int c = 0; c < 2; c++){
    int idx = c * 256 + tid;
    int row = idx >> 3;
    int col = (idx & 7) * 8;
    *(u16x8*)(wb + (size_t)(bm0 + row) * 256 + e * 64 + col) = *(const u16x8*)(&epi[row][col]);
  }
}

// ============ G3: Y = wb @ UfT; x_new = xold + x0*(bias + Y); fused next-gate ============
// 128x128 tile, 4 waves each 64x64, BK=32. Epilogue: 2 iters x 8-wide (16B/lane
// for all bf16 streams — x0b/xst reads and xst write), 16 threads/row.
template<int MODE, bool X0BF>
__global__ __launch_bounds__(256, 4) void gemm3_k(const unsigned short* __restrict__ A,
                                                  const unsigned short* __restrict__ BT,
                                                  const float* __restrict__ x0f,
                                                  const unsigned short* __restrict__ x0b,
                                                  unsigned short* __restrict__ xst,
                                                  const float* __restrict__ biasrow,
                                                  float* __restrict__ out,
                                                  const unsigned short* __restrict__ gw16,
                                                  float* __restrict__ plog){
  const int bm0 = blockIdx.x * 128;
  const int bn0 = blockIdx.y * 128;
  const int tid = threadIdx.x;
  const int lane = tid & 63;
  const int wv = tid >> 6;
  const int wm = wv >> 1, wn = wv & 1;

  __shared__ __align__(16) char smraw[20480];
  unsigned short (*As)[40] = (unsigned short (*)[40])smraw;
  unsigned short (*Bs)[40] = (unsigned short (*)[40])(smraw + 10240);
  float (*epi)[132] = (float (*)[132])smraw;

  f32x4 acc[4][4] = {};
  const int arow = tid >> 2;
  const int aseg = tid & 3;

  u16x8 ar0 = *(const u16x8*)(A + (size_t)(bm0 + arow) * 256 + aseg * 8);
  u16x8 ar1 = *(const u16x8*)(A + (size_t)(bm0 + arow + 64) * 256 + aseg * 8);
  u16x8 br0 = *(const u16x8*)(BT + (size_t)(bn0 + arow) * 256 + aseg * 8);
  u16x8 br1 = *(const u16x8*)(BT + (size_t)(bn0 + arow + 64) * 256 + aseg * 8);

  for (int k0 = 0; k0 < 256; k0 += 32){
    __syncthreads();
    *(u16x8*)(&As[arow][aseg * 8])      = ar0;
    *(u16x8*)(&As[arow + 64][aseg * 8]) = ar1;
    *(u16x8*)(&Bs[arow][aseg * 8])      = br0;
    *(u16x8*)(&Bs[arow + 64][aseg * 8]) = br1;
    __syncthreads();
    if (k0 + 32 < 256){
      ar0 = *(const u16x8*)(A + (size_t)(bm0 + arow) * 256 + k0 + 32 + aseg * 8);
      ar1 = *(const u16x8*)(A + (size_t)(bm0 + arow + 64) * 256 + k0 + 32 + aseg * 8);
      br0 = *(const u16x8*)(BT + (size_t)(bn0 + arow) * 256 + k0 + 32 + aseg * 8);
      br1 = *(const u16x8*)(BT + (size_t)(bn0 + arow + 64) * 256 + k0 + 32 + aseg * 8);
    }
    bf16x8 af[4];
    #pragma unroll
    for (int mi = 0; mi < 4; mi++)
      af[mi] = *reinterpret_cast<const bf16x8*>(&As[wm * 64 + mi * 16 + (lane & 15)][(lane >> 4) * 8]);
    #pragma unroll
    for (int nj = 0; nj < 4; nj++){
      bf16x8 bfr = *reinterpret_cast<const bf16x8*>(&Bs[wn * 64 + nj * 16 + (lane & 15)][(lane >> 4) * 8]);
      #pragma unroll
      for (int mi = 0; mi < 4; mi++)
        acc[mi][nj] = __builtin_amdgcn_mfma_f32_16x16x32_bf16(af[mi], bfr, acc[mi][nj], 0, 0, 0);
    }
  }

  // epilogue: 4 quarter-phases of 32 rows; 2 iters x 8-wide per phase (16B/lane)
  #pragma unroll
  for (int h = 0; h < 4; h++){
    __syncthreads();
    if (wm == (h >> 1)){
      const int mib = (h & 1) * 2;
      #pragma unroll
      for (int m2 = 0; m2 < 2; m2++)
        #pragma unroll
        for (int nj = 0; nj < 4; nj++)
          #pragma unroll
          for (int q = 0; q < 4; q++)
            epi[m2 * 16 + (lane >> 4) * 4 + q][wn * 64 + nj * 16 + (lane & 15)] = acc[mib + m2][nj][q];
    }
    __syncthreads();
    #pragma unroll
    for (int c = 0; c < 2; c++){
      int idx = c * 256 + tid;
      int r = idx >> 4;
      int col = (idx & 15) * 8;
      int row = bm0 + h * 32 + r;
      size_t o = (size_t)row * Dd + bn0 + col;
      f32x4 y0 = *(const f32x4*)&epi[r][col];
      f32x4 y1 = *(const f32x4*)&epi[r][col + 4];
      f32x4 b0 = *(const f32x4*)(biasrow + bn0 + col);
      f32x4 b1 = *(const f32x4*)(biasrow + bn0 + col + 4);
      float x0v[8];
      if constexpr (X0BF){
        u16x8 xv = *(const u16x8*)(x0b + o);
        #pragma unroll
        for (int j = 0; j < 8; j++) x0v[j] = bf2f(xv[j]);
      } else {
        f32x4 v0 = *(const f32x4*)(x0f + o);
        f32x4 v1 = *(const f32x4*)(x0f + o + 4);
        #pragma unroll
        for (int j = 0; j < 4; j++){ x0v[j] = v0[j]; x0v[4 + j] = v1[j]; }
      }
      float xo[8];
      if constexpr (MODE == 0){
        #pragma unroll
        for (int j = 0; j < 8; j++) xo[j] = x0v[j];
      } else {
        u16x8 sv = *(const u16x8*)(xst + o);
        #pragma unroll
        for (int j = 0; j < 8; j++) xo[j] = bf2f(sv[j]);
      }
      float xn[8];
      #pragma unroll
      for (int j = 0; j < 4; j++){
        xn[j]     = xo[j]     + x0v[j]     * (b0[j] + y0[j]);
        xn[4 + j] = xo[4 + j] + x0v[4 + j] * (b1[j] + y1[j]);
      }
      if constexpr (MODE == 2){
        f32x4 o0, o1;
        #pragma unroll
        for (int j = 0; j < 4; j++){ o0[j] = xn[j]; o1[j] = xn[4 + j]; }
        *(f32x4*)(out + o) = o0;
        *(f32x4*)(out + o + 4) = o1;
      } else {
        u16x8 nv;
        #pragma unroll
        for (int j = 0; j < 8; j++) nv[j] = f2bf(xn[j]);
        *(u16x8*)(xst + o) = nv;
      }
      if constexpr (MODE != 2){
        float s[4];
        #pragma unroll
        for (int e = 0; e < 4; e++){
          u16x8 gv = *(const u16x8*)(gw16 + (size_t)e * Dd + bn0 + col);
          float se = 0.f;
          #pragma unroll
          for (int j = 0; j < 8; j++) se += xn[j] * bf2f(gv[j]);
          s[e] = se;
        }
        #pragma unroll
        for (int m = 1; m < 16; m <<= 1)
          #pragma unroll
          for (int e = 0; e < 4; e++) s[e] += __shfl_xor(s[e], m, 64);
        if ((tid & 15) == 0){
          f32x4 pv; pv[0] = s[0]; pv[1] = s[1]; pv[2] = s[2]; pv[3] = s[3];
          *(f32x4*)(plog + ((size_t)blockIdx.y * Bb + row) * 4) = pv;
        }
      }
    }
  }
}

extern "C" void kernel_launch(void* const* d_in, const int* in_sizes, int n_in,
                              void* d_out, int out_size, void* d_ws, size_t ws_size,
                              hipStream_t stream){
  (void)in_sizes; (void)n_in; (void)out_size;
  const float* inp  = (const float*)d_in[0];
  const float* U    = (const float*)d_in[1];
  const float* V    = (const float*)d_in[2];
  const float* C    = (const float*)d_in[3];
  const float* gw   = (const float*)d_in[4];
  const float* bias = (const float*)d_in[5];
  float* out = (float*)d_out;

  char* ws = (char*)d_ws;
  size_t o = 0;
  unsigned short* xb  = (unsigned short*)(ws + o); o += (size_t)Bb * Dd * 2;          // 33.55 MB (bf16 state)
  unsigned short* vxp = (unsigned short*)(ws + o); o += (size_t)4 * Bb * 256 * 2;     // 16.78 MB (bf16 partials)
  unsigned short* wb  = (unsigned short*)(ws + o); o += (size_t)Bb * 256 * 2;         //  4.19 MB
  float*          gsb = (float*)(ws + o);          o += (size_t)Bb * 4 * 4;           //  0.13 MB
  float*          plog= (float*)(ws + o);          o += (size_t)16 * Bb * 4 * 4;      //  2.10 MB
  unsigned short* vft = (unsigned short*)(ws + o); o += (size_t)Ll * 256 * Dd * 2;    //  3.15 MB
  unsigned short* uft = (unsigned short*)(ws + o); o += (size_t)Ll * Dd * 256 * 2;    //  3.15 MB
  unsigned short* cb16= (unsigned short*)(ws + o); o += (size_t)Ll * Ee * Rr * Rr * 2;//  0.10 MB
  unsigned short* g16 = (unsigned short*)(ws + o); o += (size_t)Ee * Dd * 2;          //  0.02 MB
  if (ws_size < o) return;
  unsigned short* x0b = nullptr;
  if (ws_size >= o + (size_t)Bb * Dd * 2){
    x0b = (unsigned short*)(ws + o); o += (size_t)Bb * Dd * 2;                        // 33.55 MB (bf16 x0)
  }
  const bool hx = (x0b != nullptr);

  prep_w_k<<<1024, 256, 0, stream>>>(U, V, C, gw, vft, uft, cb16, g16);

  for (int l = 0; l < Ll; l++){
    const unsigned short* vftl = vft + (size_t)l * 256 * Dd;
    const unsigned short* uftl = uft + (size_t)l * Dd * 256;
    const unsigned short* cbl  = cb16 + (size_t)l * Ee * Rr * Rr;
    const float* biasl = bias + (size_t)l * Dd;

    if (l == 0){
      if (hx){
        gemm1_k<1><<<dim3(Bb / 128, 2, 4), 256, 0, stream>>>(inp, vftl, vxp, x0b, g16, plog);
        gemm2_k<4><<<dim3(Bb / 64, Ee), 256, 0, stream>>>(vxp, cbl, gsb, plog, wb);
      } else {
        gate_k<<<Bb / 4, 256, 0, stream>>>(inp, g16, gsb);
        gemm1_k<2><<<dim3(Bb / 128, 2, 4), 256, 0, stream>>>(inp, vftl, vxp, nullptr, g16, plog);
        gemm2_k<0><<<dim3(Bb / 64, Ee), 256, 0, stream>>>(vxp, cbl, gsb, plog, wb);
      }
    } else {
      gemm1_k<0><<<dim3(Bb / 128, 2, 4), 256, 0, stream>>>(xb, vftl, vxp, nullptr, g16, plog);
      gemm2_k<16><<<dim3(Bb / 64, Ee), 256, 0, stream>>>(vxp, cbl, gsb, plog, wb);
    }

    dim3 g3(Bb / 128, Dd / 128);
    if (l == 0){
      if (hx) gemm3_k<0, true ><<<g3, 256, 0, stream>>>(wb, uftl, inp, x0b, xb, biasl, out, g16, plog);
      else    gemm3_k<0, false><<<g3, 256, 0, stream>>>(wb, uftl, inp, x0b, xb, biasl, out, g16, plog);
    } else if (l == 1){
      if (hx) gemm3_k<1, true ><<<g3, 256, 0, stream>>>(wb, uftl, inp, x0b, xb, biasl, out, g16, plog);
      else    gemm3_k<1, false><<<g3, 256, 0, stream>>>(wb, uftl, inp, x0b, xb, biasl, out, g16, plog);
    } else {
      if (hx) gemm3_k<2, true ><<<g3, 256, 0, stream>>>(wb, uftl, inp, x0b, xb, biasl, out, g16, plog);
      else    gemm3_k<2, false><<<g3, 256, 0, stream>>>(wb, uftl, inp, x0b, xb, biasl, out, g16, plog);
    }
  }
}

// Round 15
// 199.223 us; speedup vs baseline: 1.1452x; 1.0378x over previous
//
#include <hip/hip_runtime.h>
#include <cmath>

#define Bb 8192
#define Dd 2048
#define Rr 64
#define Ee 4
#define Ll 3

typedef __bf16 bf16x8 __attribute__((ext_vector_type(8)));
typedef float f32x4 __attribute__((ext_vector_type(4)));
typedef unsigned short u16x8 __attribute__((ext_vector_type(8)));
typedef unsigned short u16x4 __attribute__((ext_vector_type(4)));

__device__ __forceinline__ unsigned short f2bf(float f){
  unsigned u = __builtin_bit_cast(unsigned, f);
  u += 0x7fffu + ((u >> 16) & 1u);
  return (unsigned short)(u >> 16);
}
__device__ __forceinline__ float bf2f(unsigned short h){
  return __builtin_bit_cast(float, ((unsigned)h) << 16);
}

// ---------------- prep: transpose/cast weights ----------------
__global__ __launch_bounds__(256) void prep_w_k(const float* __restrict__ U,
                                                const float* __restrict__ V,
                                                const float* __restrict__ C,
                                                const float* __restrict__ gw,
                                                unsigned short* __restrict__ VfT,
                                                unsigned short* __restrict__ UfT,
                                                unsigned short* __restrict__ cb16,
                                                unsigned short* __restrict__ gw16){
  const int NV = Ll * 256 * Dd;
  const int NU = Ll * Dd * 256;
  const int NC = Ll * Ee * Rr * Rr;
  const int NG = Ee * Dd;
  const int total = NV + NU + NC + NG;
  for (int idx = blockIdx.x * blockDim.x + threadIdx.x; idx < total; idx += gridDim.x * blockDim.x){
    if (idx < NV){
      int l = idx / (256 * Dd); int rem = idx - l * 256 * Dd;
      int n = rem / Dd, d = rem - n * Dd;
      int e = n >> 6, r = n & 63;
      VfT[idx] = f2bf(V[(((size_t)l * Ee + e) * Dd + d) * Rr + r]);
    } else if (idx < NV + NU){
      int j = idx - NV;
      int l = j / (Dd * 256); int rem = j - l * Dd * 256;
      int d = rem / 256, k = rem - d * 256;
      int e = k >> 6, s = k & 63;
      UfT[j] = f2bf(U[(((size_t)l * Ee + e) * Dd + d) * Rr + s]);
    } else if (idx < NV + NU + NC){
      int j = idx - NV - NU;
      cb16[j] = f2bf(C[j]);
    } else {
      int j = idx - NV - NU - NC;
      gw16[j] = f2bf(gw[j]);
    }
  }
}

// ---------------- gate (fallback, fp32 input): one wave per row ----------------
__global__ __launch_bounds__(256) void gate_k(const float* __restrict__ xv,
                                              const unsigned short* __restrict__ gw16,
                                              float* __restrict__ gs){
  const int lane = threadIdx.x & 63;
  const int w = threadIdx.x >> 6;
  const int row = blockIdx.x * 4 + w;
  float s0 = 0.f, s1 = 0.f, s2 = 0.f, s3 = 0.f;
  #pragma unroll
  for (int c = 0; c < 4; c++){
    const int k = c * 512 + lane * 8;
    const float* xr = xv + (size_t)row * Dd + k;
    f32x4 v0 = *(const f32x4*)xr;
    f32x4 v1 = *(const f32x4*)(xr + 4);
    float xf[8];
    #pragma unroll
    for (int u = 0; u < 4; u++){ xf[u] = v0[u]; xf[4 + u] = v1[u]; }
    u16x8 g0v = *(const u16x8*)(gw16 + 0 * Dd + k);
    u16x8 g1v = *(const u16x8*)(gw16 + 1 * Dd + k);
    u16x8 g2v = *(const u16x8*)(gw16 + 2 * Dd + k);
    u16x8 g3v = *(const u16x8*)(gw16 + 3 * Dd + k);
    #pragma unroll
    for (int u = 0; u < 8; u++){
      s0 += xf[u] * bf2f(g0v[u]);
      s1 += xf[u] * bf2f(g1v[u]);
      s2 += xf[u] * bf2f(g2v[u]);
      s3 += xf[u] * bf2f(g3v[u]);
    }
  }
  #pragma unroll
  for (int m = 1; m < 64; m <<= 1){
    s0 += __shfl_xor(s0, m, 64);
    s1 += __shfl_xor(s1, m, 64);
    s2 += __shfl_xor(s2, m, 64);
    s3 += __shfl_xor(s3, m, 64);
  }
  if (lane == 0){
    float mx = fmaxf(fmaxf(s0, s1), fmaxf(s2, s3));
    float e0 = __expf(s0 - mx), e1 = __expf(s1 - mx), e2 = __expf(s2 - mx), e3 = __expf(s3 - mx);
    float inv = 1.f / (e0 + e1 + e2 + e3);
    f32x4 g; g[0] = e0 * inv; g[1] = e1 * inv; g[2] = e2 * inv; g[3] = e3 * inv;
    *(f32x4*)(gs + (size_t)row * 4) = g;
  }
}

// ============ G1: T = X @ VfT, split-K=4, bf16 partials ============
// 128x128 tile, 4 waves each 64x64, BK=32, reg-prefetch.
// 1D grid 512, XCD-chunked swizzle; decode (z, bm, bn) with bn fastest so the
// two bn-partners (sharing a 128KB A-chunk) are adjacent within an XCD's chunk.
template<int M1>
__global__ __launch_bounds__(256) void gemm1_k(const void* __restrict__ Av,
                                               const unsigned short* __restrict__ BT,
                                               unsigned short* __restrict__ vxp,
                                               unsigned short* __restrict__ x0b,
                                               const unsigned short* __restrict__ gw16,
                                               float* __restrict__ plog){
  const int bid = blockIdx.x;                 // 512 blocks, 512%8==0
  const int swz = (bid & 7) * 64 + (bid >> 3);
  const int z   = swz >> 7;                   // /128
  const int rem = swz & 127;
  const int bm0 = (rem >> 1) * 128;
  const int bn0 = (rem & 1) * 128;
  const int kc0 = z * 512;
  const int tid = threadIdx.x;
  const int lane = tid & 63;
  const int wv = tid >> 6;
  const int wm = wv >> 1, wn = wv & 1;

  __shared__ __align__(16) char smraw[20480];
  unsigned short (*As)[40] = (unsigned short (*)[40])smraw;            // 10240 B
  unsigned short (*Bs)[40] = (unsigned short (*)[40])(smraw + 10240);  // 10240 B
  float (*epi)[132] = (float (*)[132])smraw;                           // 16896 B (union)

  f32x4 acc[4][4] = {};
  const int arow = tid >> 2;
  const int aseg = tid & 3;

  const float* Af = (const float*)Av;
  const unsigned short* Ab = (const unsigned short*)Av;
  const bool dog = (M1 == 1) && (bn0 == 0);

  float sg0[4] = {0.f, 0.f, 0.f, 0.f};
  float sg1[4] = {0.f, 0.f, 0.f, 0.f};

  f32x4 a4[4]; u16x8 ar0, ar1;
  u16x8 br0, br1;
  if constexpr (M1 != 0){
    a4[0] = *(const f32x4*)(Af + (size_t)(bm0 + arow) * Dd + kc0 + aseg * 8);
    a4[1] = *(const f32x4*)(Af + (size_t)(bm0 + arow) * Dd + kc0 + aseg * 8 + 4);
    a4[2] = *(const f32x4*)(Af + (size_t)(bm0 + arow + 64) * Dd + kc0 + aseg * 8);
    a4[3] = *(const f32x4*)(Af + (size_t)(bm0 + arow + 64) * Dd + kc0 + aseg * 8 + 4);
  } else {
    ar0 = *(const u16x8*)(Ab + (size_t)(bm0 + arow) * Dd + kc0 + aseg * 8);
    ar1 = *(const u16x8*)(Ab + (size_t)(bm0 + arow + 64) * Dd + kc0 + aseg * 8);
  }
  br0 = *(const u16x8*)(BT + (size_t)(bn0 + arow) * Dd + kc0 + aseg * 8);
  br1 = *(const u16x8*)(BT + (size_t)(bn0 + arow + 64) * Dd + kc0 + aseg * 8);

  for (int k0 = kc0; k0 < kc0 + 512; k0 += 32){
    __syncthreads();
    if constexpr (M1 != 0){
      u16x8 av0, av1;
      #pragma unroll
      for (int j = 0; j < 4; j++){
        av0[j] = f2bf(a4[0][j]); av0[4 + j] = f2bf(a4[1][j]);
        av1[j] = f2bf(a4[2][j]); av1[4 + j] = f2bf(a4[3][j]);
      }
      *(u16x8*)(&As[arow][aseg * 8])      = av0;
      *(u16x8*)(&As[arow + 64][aseg * 8]) = av1;
      if constexpr (M1 == 1){
        if (dog){
          *(u16x8*)(x0b + (size_t)(bm0 + arow) * Dd + k0 + aseg * 8)      = av0;
          *(u16x8*)(x0b + (size_t)(bm0 + arow + 64) * Dd + k0 + aseg * 8) = av1;
        }
      }
    } else {
      *(u16x8*)(&As[arow][aseg * 8])      = ar0;
      *(u16x8*)(&As[arow + 64][aseg * 8]) = ar1;
    }
    *(u16x8*)(&Bs[arow][aseg * 8])      = br0;
    *(u16x8*)(&Bs[arow + 64][aseg * 8]) = br1;
    __syncthreads();

    if constexpr (M1 == 1){
      if (dog){
        u16x8 g0v = *(const u16x8*)(gw16 + (size_t)0 * Dd + k0 + aseg * 8);
        u16x8 g1v = *(const u16x8*)(gw16 + (size_t)1 * Dd + k0 + aseg * 8);
        u16x8 g2v = *(const u16x8*)(gw16 + (size_t)2 * Dd + k0 + aseg * 8);
        u16x8 g3v = *(const u16x8*)(gw16 + (size_t)3 * Dd + k0 + aseg * 8);
        #pragma unroll
        for (int u = 0; u < 8; u++){
          float xa = (u < 4) ? a4[0][u] : a4[1][u - 4];
          float xc = (u < 4) ? a4[2][u] : a4[3][u - 4];
          float g0 = bf2f(g0v[u]), g1 = bf2f(g1v[u]), g2 = bf2f(g2v[u]), g3 = bf2f(g3v[u]);
          sg0[0] += xa * g0; sg0[1] += xa * g1; sg0[2] += xa * g2; sg0[3] += xa * g3;
          sg1[0] += xc * g0; sg1[1] += xc * g1; sg1[2] += xc * g2; sg1[3] += xc * g3;
        }
      }
    }

    int kn = k0 + 32;
    if (kn < kc0 + 512){
      if constexpr (M1 != 0){
        a4[0] = *(const f32x4*)(Af + (size_t)(bm0 + arow) * Dd + kn + aseg * 8);
        a4[1] = *(const f32x4*)(Af + (size_t)(bm0 + arow) * Dd + kn + aseg * 8 + 4);
        a4[2] = *(const f32x4*)(Af + (size_t)(bm0 + arow + 64) * Dd + kn + aseg * 8);
        a4[3] = *(const f32x4*)(Af + (size_t)(bm0 + arow + 64) * Dd + kn + aseg * 8 + 4);
      } else {
        ar0 = *(const u16x8*)(Ab + (size_t)(bm0 + arow) * Dd + kn + aseg * 8);
        ar1 = *(const u16x8*)(Ab + (size_t)(bm0 + arow + 64) * Dd + kn + aseg * 8);
      }
      br0 = *(const u16x8*)(BT + (size_t)(bn0 + arow) * Dd + kn + aseg * 8);
      br1 = *(const u16x8*)(BT + (size_t)(bn0 + arow + 64) * Dd + kn + aseg * 8);
    }

    bf16x8 af[4];
    #pragma unroll
    for (int mi = 0; mi < 4; mi++)
      af[mi] = *reinterpret_cast<const bf16x8*>(&As[wm * 64 + mi * 16 + (lane & 15)][(lane >> 4) * 8]);
    #pragma unroll
    for (int nj = 0; nj < 4; nj++){
      bf16x8 bfr = *reinterpret_cast<const bf16x8*>(&Bs[wn * 64 + nj * 16 + (lane & 15)][(lane >> 4) * 8]);
      #pragma unroll
      for (int mi = 0; mi < 4; mi++)
        acc[mi][nj] = __builtin_amdgcn_mfma_f32_16x16x32_bf16(af[mi], bfr, acc[mi][nj], 0, 0, 0);
    }
  }

  if constexpr (M1 == 1){
    if (dog){
      #pragma unroll
      for (int e = 0; e < 4; e++){
        sg0[e] += __shfl_xor(sg0[e], 1, 64); sg0[e] += __shfl_xor(sg0[e], 2, 64);
        sg1[e] += __shfl_xor(sg1[e], 1, 64); sg1[e] += __shfl_xor(sg1[e], 2, 64);
      }
      if (aseg == 0){
        f32x4 p0; p0[0] = sg0[0]; p0[1] = sg0[1]; p0[2] = sg0[2]; p0[3] = sg0[3];
        f32x4 p1; p1[0] = sg1[0]; p1[1] = sg1[1]; p1[2] = sg1[2]; p1[3] = sg1[3];
        *(f32x4*)(plog + ((size_t)z * Bb + bm0 + arow) * 4) = p0;
        *(f32x4*)(plog + ((size_t)z * Bb + bm0 + arow + 64) * 4) = p1;
      }
    }
  }

  unsigned short* outz = vxp + (size_t)z * Bb * 256;
  #pragma unroll
  for (int h = 0; h < 4; h++){
    __syncthreads();
    if (wm == (h >> 1)){
      const int mib = (h & 1) * 2;
      #pragma unroll
      for (int m2 = 0; m2 < 2; m2++)
        #pragma unroll
        for (int nj = 0; nj < 4; nj++)
          #pragma unroll
          for (int q = 0; q < 4; q++)
            epi[m2 * 16 + (lane >> 4) * 4 + q][wn * 64 + nj * 16 + (lane & 15)] = acc[mib + m2][nj][q];
    }
    __syncthreads();
    #pragma unroll
    for (int c = 0; c < 2; c++){
      int idx = c * 256 + tid;
      int r = idx >> 4;
      int col = (idx & 15) * 8;
      f32x4 v0 = *(const f32x4*)&epi[r][col];
      f32x4 v1 = *(const f32x4*)&epi[r][col + 4];
      u16x8 ov;
      #pragma unroll
      for (int j = 0; j < 4; j++){ ov[j] = f2bf(v0[j]); ov[4 + j] = f2bf(v1[j]); }
      *(u16x8*)(outz + (size_t)(bm0 + h * 32 + r) * 256 + bn0 + col) = ov;
    }
  }
}

// ============ G2: block-diag C; sums bf16 partials ============
template<int NPART>
__global__ __launch_bounds__(256) void gemm2_k(const unsigned short* __restrict__ vxp,
                                               const unsigned short* __restrict__ cb,
                                               const float* __restrict__ gsb,
                                               const float* __restrict__ plog,
                                               unsigned short* __restrict__ wb){
  const int bm0 = blockIdx.x * 64;
  const int e   = blockIdx.y;
  const int tid = threadIdx.x;
  const int lane = tid & 63;
  const int wv = tid >> 6;
  const int wm = wv >> 1, wn = wv & 1;

  __shared__ __align__(16) char smraw[19456];
  unsigned short (*As)[72] = (unsigned short (*)[72])smraw;
  unsigned short (*Bs)[72] = (unsigned short (*)[72])(smraw + 9216);
  float (*gs_l)[4] = (float (*)[4])(smraw + 18432);
  unsigned short (*epi)[72] = (unsigned short (*)[72])smraw;

  if constexpr (NPART > 0){
    int r = tid >> 2, q = tid & 3;
    f32x4 s = {0.f, 0.f, 0.f, 0.f};
    #pragma unroll
    for (int ci = 0; ci < NPART / 4; ci++)
      s += *(const f32x4*)(plog + ((size_t)(q * (NPART / 4) + ci) * Bb + bm0 + r) * 4);
    #pragma unroll
    for (int j = 0; j < 4; j++){
      s[j] += __shfl_xor(s[j], 1, 64);
      s[j] += __shfl_xor(s[j], 2, 64);
    }
    if (q == 0){
      float mx = fmaxf(fmaxf(s[0], s[1]), fmaxf(s[2], s[3]));
      float e0 = __expf(s[0] - mx), e1 = __expf(s[1] - mx), e2 = __expf(s[2] - mx), e3 = __expf(s[3] - mx);
      float inv = 1.f / (e0 + e1 + e2 + e3);
      f32x4 g; g[0] = e0 * inv; g[1] = e1 * inv; g[2] = e2 * inv; g[3] = e3 * inv;
      *(f32x4*)&gs_l[r][0] = g;
    }
  } else {
    if (tid < 64) *(f32x4*)&gs_l[tid][0] = *(const f32x4*)(gsb + (size_t)(bm0 + tid) * 4);
  }

  const int arow = tid >> 2;
  const int aseg = tid & 3;

  float tv[16];
  #pragma unroll
  for (int j = 0; j < 16; j++) tv[j] = 0.f;
  #pragma unroll
  for (int z = 0; z < 4; z++){
    const unsigned short* vz = vxp + ((size_t)z * Bb + bm0 + arow) * 256 + e * 64 + aseg * 16;
    u16x8 p0 = *(const u16x8*)vz;
    u16x8 p1 = *(const u16x8*)(vz + 8);
    #pragma unroll
    for (int j = 0; j < 8; j++){ tv[j] += bf2f(p0[j]); tv[8 + j] += bf2f(p1[j]); }
  }
  u16x8 av0, av1;
  #pragma unroll
  for (int j = 0; j < 4; j++){
    av0[j] = f2bf(tanhf(tv[j]));     av0[4 + j] = f2bf(tanhf(tv[4 + j]));
    av1[j] = f2bf(tanhf(tv[8 + j])); av1[4 + j] = f2bf(tanhf(tv[12 + j]));
  }
  *(u16x8*)(&As[arow][aseg * 16]) = av0;
  *(u16x8*)(&As[arow][aseg * 16 + 8]) = av1;
  *(u16x8*)(&Bs[arow][aseg * 16])     = *(const u16x8*)(cb + e * 4096 + arow * 64 + aseg * 16);
  *(u16x8*)(&Bs[arow][aseg * 16 + 8]) = *(const u16x8*)(cb + e * 4096 + arow * 64 + aseg * 16 + 8);
  __syncthreads();

  f32x4 acc[2][2] = {};
  #pragma unroll
  for (int kk = 0; kk < 2; kk++){
    bf16x8 af[2];
    #pragma unroll
    for (int mi = 0; mi < 2; mi++)
      af[mi] = *reinterpret_cast<const bf16x8*>(&As[wm * 32 + mi * 16 + (lane & 15)][kk * 32 + (lane >> 4) * 8]);
    #pragma unroll
    for (int nj = 0; nj < 2; nj++){
      bf16x8 bfr = *reinterpret_cast<const bf16x8*>(&Bs[wn * 32 + nj * 16 + (lane & 15)][kk * 32 + (lane >> 4) * 8]);
      #pragma unroll
      for (int mi = 0; mi < 2; mi++)
        acc[mi][nj] = __builtin_amdgcn_mfma_f32_16x16x32_bf16(af[mi], bfr, acc[mi][nj], 0, 0, 0);
    }
  }

  __syncthreads();
  #pragma unroll
  for (int mi = 0; mi < 2; mi++)
    #pragma unroll
    for (int nj = 0; nj < 2; nj++)
      #pragma unroll
      for (int q = 0; q < 4; q++){
        int row = wm * 32 + mi * 16 + (lane >> 4) * 4 + q;
        int col = wn * 32 + nj * 16 + (lane & 15);
        float g = gs_l[row][e];
        epi[row][col] = f2bf(g * tanhf(acc[mi][nj][q]));
      }
  __syncthreads();
  #pragma unroll
  for (int c = 0; c < 2; c++){
    int idx = c * 256 + tid;
    int row = idx >> 3;
    int col = (idx & 7) * 8;
    *(u16x8*)(wb + (size_t)(bm0 + row) * 256 + e * 64 + col) = *(const u16x8*)(&epi[row][col]);
  }
}

// ============ G3: Y = wb @ UfT; x_new = xold + x0*(bias + Y); fused next-gate ============
// 128x128 tile, BK=32, 16B/lane epilogue. 1D grid 1024 with XCD-chunked swizzle:
// each XCD owns 8 consecutive bm panels x all bn (wb slice + uft stay L2-hot).
template<int MODE, bool X0BF>
__global__ __launch_bounds__(256, 4) void gemm3_k(const unsigned short* __restrict__ A,
                                                  const unsigned short* __restrict__ BT,
                                                  const float* __restrict__ x0f,
                                                  const unsigned short* __restrict__ x0b,
                                                  unsigned short* __restrict__ xst,
                                                  const float* __restrict__ biasrow,
                                                  float* __restrict__ out,
                                                  const unsigned short* __restrict__ gw16,
                                                  float* __restrict__ plog){
  const int bid = blockIdx.x;                  // 1024 blocks, 1024%8==0
  const int swz = (bid & 7) * 128 + (bid >> 3);
  const int bm0 = (swz >> 4) * 128;
  const int bn0i = swz & 15;
  const int bn0 = bn0i * 128;
  const int tid = threadIdx.x;
  const int lane = tid & 63;
  const int wv = tid >> 6;
  const int wm = wv >> 1, wn = wv & 1;

  __shared__ __align__(16) char smraw[20480];
  unsigned short (*As)[40] = (unsigned short (*)[40])smraw;
  unsigned short (*Bs)[40] = (unsigned short (*)[40])(smraw + 10240);
  float (*epi)[132] = (float (*)[132])smraw;

  f32x4 acc[4][4] = {};
  const int arow = tid >> 2;
  const int aseg = tid & 3;

  u16x8 ar0 = *(const u16x8*)(A + (size_t)(bm0 + arow) * 256 + aseg * 8);
  u16x8 ar1 = *(const u16x8*)(A + (size_t)(bm0 + arow + 64) * 256 + aseg * 8);
  u16x8 br0 = *(const u16x8*)(BT + (size_t)(bn0 + arow) * 256 + aseg * 8);
  u16x8 br1 = *(const u16x8*)(BT + (size_t)(bn0 + arow + 64) * 256 + aseg * 8);

  for (int k0 = 0; k0 < 256; k0 += 32){
    __syncthreads();
    *(u16x8*)(&As[arow][aseg * 8])      = ar0;
    *(u16x8*)(&As[arow + 64][aseg * 8]) = ar1;
    *(u16x8*)(&Bs[arow][aseg * 8])      = br0;
    *(u16x8*)(&Bs[arow + 64][aseg * 8]) = br1;
    __syncthreads();
    if (k0 + 32 < 256){
      ar0 = *(const u16x8*)(A + (size_t)(bm0 + arow) * 256 + k0 + 32 + aseg * 8);
      ar1 = *(const u16x8*)(A + (size_t)(bm0 + arow + 64) * 256 + k0 + 32 + aseg * 8);
      br0 = *(const u16x8*)(BT + (size_t)(bn0 + arow) * 256 + k0 + 32 + aseg * 8);
      br1 = *(const u16x8*)(BT + (size_t)(bn0 + arow + 64) * 256 + k0 + 32 + aseg * 8);
    }
    bf16x8 af[4];
    #pragma unroll
    for (int mi = 0; mi < 4; mi++)
      af[mi] = *reinterpret_cast<const bf16x8*>(&As[wm * 64 + mi * 16 + (lane & 15)][(lane >> 4) * 8]);
    #pragma unroll
    for (int nj = 0; nj < 4; nj++){
      bf16x8 bfr = *reinterpret_cast<const bf16x8*>(&Bs[wn * 64 + nj * 16 + (lane & 15)][(lane >> 4) * 8]);
      #pragma unroll
      for (int mi = 0; mi < 4; mi++)
        acc[mi][nj] = __builtin_amdgcn_mfma_f32_16x16x32_bf16(af[mi], bfr, acc[mi][nj], 0, 0, 0);
    }
  }

  // epilogue: 4 quarter-phases of 32 rows; 2 iters x 8-wide per phase (16B/lane)
  #pragma unroll
  for (int h = 0; h < 4; h++){
    __syncthreads();
    if (wm == (h >> 1)){
      const int mib = (h & 1) * 2;
      #pragma unroll
      for (int m2 = 0; m2 < 2; m2++)
        #pragma unroll
        for (int nj = 0; nj < 4; nj++)
          #pragma unroll
          for (int q = 0; q < 4; q++)
            epi[m2 * 16 + (lane >> 4) * 4 + q][wn * 64 + nj * 16 + (lane & 15)] = acc[mib + m2][nj][q];
    }
    __syncthreads();
    #pragma unroll
    for (int c = 0; c < 2; c++){
      int idx = c * 256 + tid;
      int r = idx >> 4;
      int col = (idx & 15) * 8;
      int row = bm0 + h * 32 + r;
      size_t o = (size_t)row * Dd + bn0 + col;
      f32x4 y0 = *(const f32x4*)&epi[r][col];
      f32x4 y1 = *(const f32x4*)&epi[r][col + 4];
      f32x4 b0 = *(const f32x4*)(biasrow + bn0 + col);
      f32x4 b1 = *(const f32x4*)(biasrow + bn0 + col + 4);
      float x0v[8];
      if constexpr (X0BF){
        u16x8 xv = *(const u16x8*)(x0b + o);
        #pragma unroll
        for (int j = 0; j < 8; j++) x0v[j] = bf2f(xv[j]);
      } else {
        f32x4 v0 = *(const f32x4*)(x0f + o);
        f32x4 v1 = *(const f32x4*)(x0f + o + 4);
        #pragma unroll
        for (int j = 0; j < 4; j++){ x0v[j] = v0[j]; x0v[4 + j] = v1[j]; }
      }
      float xo[8];
      if constexpr (MODE == 0){
        #pragma unroll
        for (int j = 0; j < 8; j++) xo[j] = x0v[j];
      } else {
        u16x8 sv = *(const u16x8*)(xst + o);
        #pragma unroll
        for (int j = 0; j < 8; j++) xo[j] = bf2f(sv[j]);
      }
      float xn[8];
      #pragma unroll
      for (int j = 0; j < 4; j++){
        xn[j]     = xo[j]     + x0v[j]     * (b0[j] + y0[j]);
        xn[4 + j] = xo[4 + j] + x0v[4 + j] * (b1[j] + y1[j]);
      }
      if constexpr (MODE == 2){
        f32x4 o0, o1;
        #pragma unroll
        for (int j = 0; j < 4; j++){ o0[j] = xn[j]; o1[j] = xn[4 + j]; }
        *(f32x4*)(out + o) = o0;
        *(f32x4*)(out + o + 4) = o1;
      } else {
        u16x8 nv;
        #pragma unroll
        for (int j = 0; j < 8; j++) nv[j] = f2bf(xn[j]);
        *(u16x8*)(xst + o) = nv;
      }
      if constexpr (MODE != 2){
        float s[4];
        #pragma unroll
        for (int e = 0; e < 4; e++){
          u16x8 gv = *(const u16x8*)(gw16 + (size_t)e * Dd + bn0 + col);
          float se = 0.f;
          #pragma unroll
          for (int j = 0; j < 8; j++) se += xn[j] * bf2f(gv[j]);
          s[e] = se;
        }
        #pragma unroll
        for (int m = 1; m < 16; m <<= 1)
          #pragma unroll
          for (int e = 0; e < 4; e++) s[e] += __shfl_xor(s[e], m, 64);
        if ((tid & 15) == 0){
          f32x4 pv; pv[0] = s[0]; pv[1] = s[1]; pv[2] = s[2]; pv[3] = s[3];
          *(f32x4*)(plog + ((size_t)bn0i * Bb + row) * 4) = pv;
        }
      }
    }
  }
}

extern "C" void kernel_launch(void* const* d_in, const int* in_sizes, int n_in,
                              void* d_out, int out_size, void* d_ws, size_t ws_size,
                              hipStream_t stream){
  (void)in_sizes; (void)n_in; (void)out_size;
  const float* inp  = (const float*)d_in[0];
  const float* U    = (const float*)d_in[1];
  const float* V    = (const float*)d_in[2];
  const float* C    = (const float*)d_in[3];
  const float* gw   = (const float*)d_in[4];
  const float* bias = (const float*)d_in[5];
  float* out = (float*)d_out;

  char* ws = (char*)d_ws;
  size_t o = 0;
  unsigned short* xb  = (unsigned short*)(ws + o); o += (size_t)Bb * Dd * 2;          // 33.55 MB (bf16 state)
  unsigned short* vxp = (unsigned short*)(ws + o); o += (size_t)4 * Bb * 256 * 2;     // 16.78 MB (bf16 partials)
  unsigned short* wb  = (unsigned short*)(ws + o); o += (size_t)Bb * 256 * 2;         //  4.19 MB
  float*          gsb = (float*)(ws + o);          o += (size_t)Bb * 4 * 4;           //  0.13 MB
  float*          plog= (float*)(ws + o);          o += (size_t)16 * Bb * 4 * 4;      //  2.10 MB
  unsigned short* vft = (unsigned short*)(ws + o); o += (size_t)Ll * 256 * Dd * 2;    //  3.15 MB
  unsigned short* uft = (unsigned short*)(ws + o); o += (size_t)Ll * Dd * 256 * 2;    //  3.15 MB
  unsigned short* cb16= (unsigned short*)(ws + o); o += (size_t)Ll * Ee * Rr * Rr * 2;//  0.10 MB
  unsigned short* g16 = (unsigned short*)(ws + o); o += (size_t)Ee * Dd * 2;          //  0.02 MB
  if (ws_size < o) return;
  unsigned short* x0b = nullptr;
  if (ws_size >= o + (size_t)Bb * Dd * 2){
    x0b = (unsigned short*)(ws + o); o += (size_t)Bb * Dd * 2;                        // 33.55 MB (bf16 x0)
  }
  const bool hx = (x0b != nullptr);

  prep_w_k<<<1024, 256, 0, stream>>>(U, V, C, gw, vft, uft, cb16, g16);

  for (int l = 0; l < Ll; l++){
    const unsigned short* vftl = vft + (size_t)l * 256 * Dd;
    const unsigned short* uftl = uft + (size_t)l * Dd * 256;
    const unsigned short* cbl  = cb16 + (size_t)l * Ee * Rr * Rr;
    const float* biasl = bias + (size_t)l * Dd;

    if (l == 0){
      if (hx){
        gemm1_k<1><<<512, 256, 0, stream>>>(inp, vftl, vxp, x0b, g16, plog);
        gemm2_k<4><<<dim3(Bb / 64, Ee), 256, 0, stream>>>(vxp, cbl, gsb, plog, wb);
      } else {
        gate_k<<<Bb / 4, 256, 0, stream>>>(inp, g16, gsb);
        gemm1_k<2><<<512, 256, 0, stream>>>(inp, vftl, vxp, nullptr, g16, plog);
        gemm2_k<0><<<dim3(Bb / 64, Ee), 256, 0, stream>>>(vxp, cbl, gsb, plog, wb);
      }
    } else {
      gemm1_k<0><<<512, 256, 0, stream>>>(xb, vftl, vxp, nullptr, g16, plog);
      gemm2_k<16><<<dim3(Bb / 64, Ee), 256, 0, stream>>>(vxp, cbl, gsb, plog, wb);
    }

    if (l == 0){
      if (hx) gemm3_k<0, true ><<<1024, 256, 0, stream>>>(wb, uftl, inp, x0b, xb, biasl, out, g16, plog);
      else    gemm3_k<0, false><<<1024, 256, 0, stream>>>(wb, uftl, inp, x0b, xb, biasl, out, g16, plog);
    } else if (l == 1){
      if (hx) gemm3_k<1, true ><<<1024, 256, 0, stream>>>(wb, uftl, inp, x0b, xb, biasl, out, g16, plog);
      else    gemm3_k<1, false><<<1024, 256, 0, stream>>>(wb, uftl, inp, x0b, xb, biasl, out, g16, plog);
    } else {
      if (hx) gemm3_k<2, true ><<<1024, 256, 0, stream>>>(wb, uftl, inp, x0b, xb, biasl, out, g16, plog);
      else    gemm3_k<2, false><<<1024, 256, 0, stream>>>(wb, uftl, inp, x0b, xb, biasl, out, g16, plog);
    }
  }
}